// Round 2
// baseline (2474.970 us; speedup 1.0000x reference)
//
#include <hip/hip_runtime.h>
#include <hip/hip_bf16.h>

typedef __attribute__((ext_vector_type(8))) __bf16 bf16x8;
typedef __attribute__((ext_vector_type(4))) float f32x4;
typedef __hip_bfloat16 bf16_t;

#define BB 8192L
#define HH 2048L
#define BH (8192L*2048L)      // elements per full [B,H] slab
#define WUNIT (2048L*2048L)   // elements per HxH weight unit
#define WT (3L*2048L*2048L)   // elements per [3,H,H] weight tensor (also Wout 2048x6144)

struct SlabMap { int a[6]; int w[6]; };

__device__ __forceinline__ void gload_lds16(const void* g, void* l) {
    __builtin_amdgcn_global_load_lds((__attribute__((address_space(1))) void*)g,
                                     (__attribute__((address_space(3))) void*)l, 16, 0, 0);
}

// C[slab][M=Bc, N=2048] = A[slab][M,K] @ W[widx][N,K]^T + bias[widx]
// 128x128 tile, BK=64, 256 threads = 4 waves (2x2 of 64x64), mfma_f32_16x16x32_bf16.
// LDS tiles [128][64] bf16, XOR swizzle: chunk ^= row&7 (16B chunks); source pre-swizzled
// since global_load_lds writes linearly (rule 21: both-sides-or-neither).
template<bool OUT_F32, bool FUSEK>
__global__ __launch_bounds__(256, 2)
void gemm_bt(const bf16_t* __restrict__ A, long aslab, SlabMap map, int mshift,
             const bf16_t* __restrict__ Bw, int ldb,
             const float* __restrict__ bias,
             void* __restrict__ Cout, long cslab, int K)
{
    __shared__ unsigned short sA[128*64];
    __shared__ unsigned short sB[128*64];
    char* sAb = (char*)sA;
    char* sBb = (char*)sB;
    const int t = threadIdx.x;
    const int lane = t & 63;
    const int w = t >> 6;
    const int wr = w >> 1, wc = w & 1;

    const int  sl    = (int)(blockIdx.y >> mshift);
    const long rowA0 = (long)(blockIdx.y & ((1u << mshift) - 1u)) * 128;
    const long rowB0 = (long)blockIdx.x * 128;
    const bf16_t* Ab   = FUSEK ? A : (A + (long)map.a[sl] * aslab);
    const bf16_t* Wb   = Bw + (long)map.w[sl] * WUNIT;
    const float*  be   = bias + (long)map.w[sl] * HH;

    f32x4 acc[4][4];
    const f32x4 zero = {0.f, 0.f, 0.f, 0.f};
    #pragma unroll
    for (int i = 0; i < 4; ++i)
        #pragma unroll
        for (int j = 0; j < 4; ++j) acc[i][j] = zero;

    const int srow = t >> 3;                  // 0..31
    const int schunk = (t & 7) ^ (srow & 7);  // pre-swizzled source 16B-slot
    const int ldst = w * 1024;                // wave-uniform LDS base within each 4KB issue

    for (int k0 = 0; k0 < K; k0 += 64) {
        const bf16_t* Aeff; int ka;
        if constexpr (FUSEK) { Aeff = A + (long)(k0 >> 11) * aslab; ka = k0 & 2047; }
        else                 { Aeff = Ab; ka = k0; }
        __syncthreads();   // previous tile's reads done before overwrite
        #pragma unroll
        for (int i = 0; i < 4; ++i) {
            const bf16_t* ga = Aeff + (rowA0 + i*32 + srow) * HH + (ka + schunk*8);
            gload_lds16(ga, sAb + i*4096 + ldst);
        }
        #pragma unroll
        for (int i = 0; i < 4; ++i) {
            const bf16_t* gb = Wb + (rowB0 + i*32 + srow) * (long)ldb + (k0 + schunk*8);
            gload_lds16(gb, sBb + i*4096 + ldst);
        }
        __syncthreads();   // drains vmcnt -> tile visible
        #pragma unroll
        for (int s = 0; s < 2; ++s) {
            bf16x8 af[4], bfr[4];
            #pragma unroll
            for (int i = 0; i < 4; ++i) {
                const int rowA = wr*64 + i*16 + (lane & 15);
                const int offA = rowA*128 + ((s*64 + ((lane >> 4) * 16)) ^ ((rowA & 7) << 4));
                af[i] = *(const bf16x8*)(sAb + offA);
                const int rowB = wc*64 + i*16 + (lane & 15);
                const int offB = rowB*128 + ((s*64 + ((lane >> 4) * 16)) ^ ((rowB & 7) << 4));
                bfr[i] = *(const bf16x8*)(sBb + offB);
            }
            #pragma unroll
            for (int i = 0; i < 4; ++i)
                #pragma unroll
                for (int j = 0; j < 4; ++j)
                    acc[i][j] = __builtin_amdgcn_mfma_f32_16x16x32_bf16(af[i], bfr[j], acc[i][j], 0, 0, 0);
        }
    }

    // C/D layout: col = lane&15, row = (lane>>4)*4 + reg  [m89/m91]
    const long crow0 = rowA0 + wr*64 + ((lane >> 4) * 4);
    const int  ccol0 = (int)rowB0 + wc*64 + (lane & 15);
    const long cbase = (long)sl * cslab;
    #pragma unroll
    for (int i = 0; i < 4; ++i) {
        #pragma unroll
        for (int j = 0; j < 4; ++j) {
            const int col = ccol0 + j*16;
            const float bv = be[col];
            #pragma unroll
            for (int r = 0; r < 4; ++r) {
                const long row = crow0 + i*16 + r;
                const float val = acc[i][j][r] + bv;
                if constexpr (OUT_F32) ((float*)Cout)[cbase + row*HH + col] = val;
                else ((bf16_t*)Cout)[cbase + row*HH + col] = __float2bfloat16(val);
            }
        }
    }
}

__global__ __launch_bounds__(256)
void f2b_kernel(const float* __restrict__ in, bf16_t* __restrict__ out, long n)
{
    long i = ((long)blockIdx.x * 256 + threadIdx.x) * 4;
    const long stride = (long)gridDim.x * 256 * 4;
    for (; i < n; i += stride) {
        const float4 v = *(const float4*)(in + i);
        __hip_bfloat162 lo, hi;
        lo.x = __float2bfloat16(v.x); lo.y = __float2bfloat16(v.y);
        hi.x = __float2bfloat16(v.z); hi.y = __float2bfloat16(v.w);
        *(__hip_bfloat162*)(out + i)     = lo;
        *(__hip_bfloat162*)(out + i + 2) = hi;
    }
}

// one wave per (v, b, head): q_len=1 attention over the 2 other views.
__global__ __launch_bounds__(256)
void attn_kernel(const bf16_t* __restrict__ q2, const bf16_t* __restrict__ k2,
                 const bf16_t* __restrict__ v2, bf16_t* __restrict__ ctx, int bshift)
{
    const long gw = (long)blockIdx.x * 4 + (threadIdx.x >> 6);
    const int lane = threadIdx.x & 63;
    const int  v_  = (int)(gw >> (bshift + 4));
    const long rem = gw & ((1L << (bshift + 4)) - 1);
    const long b   = rem >> 4;
    const int  n   = (int)(rem & 15);
    const long base = ((((long)v_ << bshift) + b)) * HH + (long)n * 128 + lane * 2;

    const __hip_bfloat162 qv = *(const __hip_bfloat162*)(q2 + base);
    const float q0 = __bfloat162float(qv.x), q1 = __bfloat162float(qv.y);
    float s[2], va[2], vb[2];
    #pragma unroll
    for (int j = 0; j < 2; ++j) {
        const long kb = ((((long)(v_*2 + j) << bshift) + b)) * HH + (long)n * 128 + lane * 2;
        const __hip_bfloat162 kv = *(const __hip_bfloat162*)(k2 + kb);
        float p = q0 * __bfloat162float(kv.x) + q1 * __bfloat162float(kv.y);
        #pragma unroll
        for (int off = 32; off > 0; off >>= 1) p += __shfl_xor(p, off);
        s[j] = p;
        const __hip_bfloat162 vv = *(const __hip_bfloat162*)(v2 + kb);
        va[j] = __bfloat162float(vv.x); vb[j] = __bfloat162float(vv.y);
    }
    const float scale = 0.08838834764831845f; // 1/sqrt(128)
    const float s0 = s[0] * scale, s1 = s[1] * scale;
    const float m  = fmaxf(s0, s1);
    const float e0 = expf(s0 - m), e1 = expf(s1 - m);
    const float inv = 1.0f / (e0 + e1);
    const float a0 = e0 * inv, a1 = e1 * inv;
    __hip_bfloat162 o;
    o.x = __float2bfloat16(a0 * va[0] + a1 * va[1]);
    o.y = __float2bfloat16(a0 * vb[0] + a1 * vb[1]);
    *(__hip_bfloat162*)(ctx + base) = o;
}

// residual (views[0] chunk) + LayerNorm, one block per row
__global__ __launch_bounds__(256)
void ln_kernel(const float* __restrict__ proj, const float* __restrict__ v0,
               const float* __restrict__ gamma, const float* __restrict__ beta,
               float* __restrict__ out)
{
    const long b = blockIdx.x;
    const int t = threadIdx.x;
    const float* pr = proj + b * HH;
    const float* vw = v0 + b * HH;
    float x[8]; float s = 0.f, s2 = 0.f;
    #pragma unroll
    for (int k = 0; k < 8; ++k) {
        const int idx = t + k * 256;
        x[k] = vw[idx] + pr[idx];
        s += x[k]; s2 += x[k] * x[k];
    }
    #pragma unroll
    for (int off = 32; off > 0; off >>= 1) { s += __shfl_xor(s, off); s2 += __shfl_xor(s2, off); }
    __shared__ float rs[4], rs2[4];
    if ((t & 63) == 0) { rs[t >> 6] = s; rs2[t >> 6] = s2; }
    __syncthreads();
    s  = rs[0] + rs[1] + rs[2] + rs[3];
    s2 = rs2[0] + rs2[1] + rs2[2] + rs2[3];
    const float mu  = s * (1.0f / 2048.0f);
    const float var = s2 * (1.0f / 2048.0f) - mu * mu;
    const float rstd = rsqrtf(var + 1e-5f);
    #pragma unroll
    for (int k = 0; k < 8; ++k) {
        const int idx = t + k * 256;
        out[b * HH + idx] = (x[k] - mu) * rstd * gamma[idx] + beta[idx];
    }
}

extern "C" void kernel_launch(void* const* d_in, const int* in_sizes, int n_in,
                              void* d_out, int out_size, void* d_ws, size_t ws_size,
                              hipStream_t stream)
{
    const float* views = (const float*)d_in[0];
    const float* Wf[8] = { (const float*)d_in[1],  (const float*)d_in[3],
                           (const float*)d_in[5],  (const float*)d_in[7],
                           (const float*)d_in[9],  (const float*)d_in[11],
                           (const float*)d_in[13], (const float*)d_in[15] };
    // Wf order: Wq, Wk, Wv, Wiq, Wik, Wiv, Wo, Wout
    const float* bq   = (const float*)d_in[2];
    const float* bk   = (const float*)d_in[4];
    const float* bv   = (const float*)d_in[6];
    const float* biq  = (const float*)d_in[8];
    const float* bik  = (const float*)d_in[10];
    const float* biv  = (const float*)d_in[12];
    const float* bo   = (const float*)d_in[14];
    const float* bout = (const float*)d_in[16];
    const float* gamma= (const float*)d_in[17];
    const float* beta = (const float*)d_in[18];

    // ---- adaptive batch chunking so the workspace footprint fits ws_size ----
    // footprint = 201,326,592 B (bf16 weights) + Bc * 98,304 B (activations)
    const long WBYTES = 201326592L;
    long avail = (long)ws_size - WBYTES;
    long Bc = 8192;
    while (Bc > 128 && Bc * 98304L > avail) Bc >>= 1;
    const int mshift = __builtin_ctzl((unsigned long)Bc) - 7;  // log2(Bc/128)
    const int bshift = __builtin_ctzl((unsigned long)Bc);      // log2(Bc)
    const long S1 = Bc * HH;     // elements per [Bc,H] slab

    char* ws = (char*)d_ws;
    bf16_t* WBF = (bf16_t*)ws;
    long off = WBYTES;
    bf16_t* VBF = (bf16_t*)(ws + off); off += 3*S1*2;   // views_bf -> later q2
    bf16_t* QB  = (bf16_t*)(ws + off); off += 3*S1*2;   // q -> later ctx
    bf16_t* KB  = (bf16_t*)(ws + off); off += 3*S1*2;   // k_all -> later att_out
    bf16_t* VVB = (bf16_t*)(ws + off); off += 3*S1*2;   // v_all
    bf16_t* K2  = (bf16_t*)(ws + off); long k2off = off; off += 6*S1*2;
    bf16_t* V2  = (bf16_t*)(ws + off); off += 6*S1*2;
    float*  PROJ= (float*)(ws + k2off);                 // aliases K2 (k2 consumed by attn)

    const SlabMap mp3 = {{0,1,2,0,0,0},{0,1,2,0,0,0}};
    const SlabMap mp6 = {{1,2,0,2,0,1},{0,0,1,1,2,2}};  // a = oth[v][j], w = v
    const SlabMap mp1 = {{0,0,0,0,0,0},{0,0,0,0,0,0}};

    // ---- weights f32 -> bf16, once ----
    for (int i = 0; i < 8; ++i)
        f2b_kernel<<<8192, 256, 0, stream>>>(Wf[i], WBF + (long)i * WT, WT);

    const dim3 g3(16, 3u << mshift), g6(16, 6u << mshift), g1(16, 1u << mshift);
    const int vgrid = (int)((S1 / 1024 > 8192) ? 8192 : S1 / 1024);

    for (long b0 = 0; b0 < BB; b0 += Bc) {
        // views chunk -> bf16
        for (int v = 0; v < 3; ++v)
            f2b_kernel<<<vgrid, 256, 0, stream>>>(views + v*BH + b0*HH, VBF + v*S1, S1);
        // q / k_all / v_all (batched over views)
        gemm_bt<false,false><<<g3, 256, 0, stream>>>(VBF, S1, mp3, mshift, WBF + 0*WT, 2048, bq,  (void*)QB,  S1, 2048);
        gemm_bt<false,false><<<g3, 256, 0, stream>>>(VBF, S1, mp3, mshift, WBF + 1*WT, 2048, bk,  (void*)KB,  S1, 2048);
        gemm_bt<false,false><<<g3, 256, 0, stream>>>(VBF, S1, mp3, mshift, WBF + 2*WT, 2048, bv,  (void*)VVB, S1, 2048);
        // q2 (overwrites views_bf), k2, v2
        gemm_bt<false,false><<<g3, 256, 0, stream>>>(QB,  S1, mp3, mshift, WBF + 3*WT, 2048, biq, (void*)VBF, S1, 2048);
        gemm_bt<false,false><<<g6, 256, 0, stream>>>(KB,  S1, mp6, mshift, WBF + 4*WT, 2048, bik, (void*)K2,  S1, 2048);
        gemm_bt<false,false><<<g6, 256, 0, stream>>>(VVB, S1, mp6, mshift, WBF + 5*WT, 2048, biv, (void*)V2,  S1, 2048);
        // attention: ctx -> QB
        attn_kernel<<<(int)(12*Bc), 256, 0, stream>>>(VBF, K2, V2, QB, bshift);
        // att_out -> KB
        gemm_bt<false,false><<<g3, 256, 0, stream>>>(QB,  S1, mp3, mshift, WBF + 6*WT, 2048, bo,  (void*)KB,  S1, 2048);
        // fused projection: K=6144 batched over views' slabs of KB, f32 out (aliases K2)
        gemm_bt<true,true><<<g1, 256, 0, stream>>>(KB, S1, mp1, mshift, WBF + 7*WT, 6144, bout, (void*)PROJ, 0, 6144);
        // residual + LayerNorm
        ln_kernel<<<(int)Bc, 256, 0, stream>>>(PROJ, views + b0*HH, gamma, beta, ((float*)d_out) + b0*HH);
    }
}

// Round 3
// 2428.969 us; speedup vs baseline: 1.0189x; 1.0189x over previous
//
#include <hip/hip_runtime.h>
#include <hip/hip_bf16.h>

typedef __attribute__((ext_vector_type(8))) __bf16 bf16x8;
typedef __attribute__((ext_vector_type(4))) float f32x4;
typedef __hip_bfloat16 bf16_t;

#define BB 8192L
#define HH 2048L
#define BH (8192L*2048L)      // elements per full [B,H] slab
#define WUNIT (2048L*2048L)   // elements per HxH weight unit
#define WT (3L*2048L*2048L)   // elements per [3,H,H] weight tensor (also Wout 2048x6144)
#define LDS_TOTAL 147456      // 3 slots x (A 32KB + B 16KB)

struct SlabMap { int a[6]; int w[6]; };

__device__ __forceinline__ void gload_lds16(const void* g, void* l) {
    __builtin_amdgcn_global_load_lds((__attribute__((address_space(1))) void*)g,
                                     (__attribute__((address_space(3))) void*)l, 16, 0, 0);
}

// C[slab][M, N=2048] = A[slab][M,K] @ W[widx][N,K]^T + bias[widx]
// BM=256 x BN=128 tile, BK=64, 512 threads = 8 waves (4M x 2N, 64x64 each).
// 3-deep LDS ring: compute K-tile t from slot t%3, stage t+2 into slot (t+2)%3,
// then s_waitcnt vmcnt(6) (t+1's 6 loads landed; t+2's 6 stay IN FLIGHT) + raw
// s_barrier. One barrier per K-step, no vmcnt(0) drain in steady state (T3/T4).
// Slot (t+2)%3 was read at iter t-1; those ds_reads completed before t-1's
// barrier (lgkmcnt before MFMA), so the overwrite is race-free.
// LDS tiles [rows][64] bf16, XOR swizzle chunk ^= row&7 (16B chunks), source
// pre-swizzled since global_load_lds writes linearly (rule 21).
template<bool OUT_F32, bool FUSEK>
__global__ __launch_bounds__(512, 1)
void gemm256(const bf16_t* __restrict__ A, long aslab, SlabMap map, int mshift,
             const bf16_t* __restrict__ Bw, int ldb,
             const float* __restrict__ bias,
             void* __restrict__ Cout, long cslab, int K)
{
    extern __shared__ char lds[];
    const int tid  = threadIdx.x;
    const int lane = tid & 63;
    const int w    = tid >> 6;
    const int wm   = w >> 1, wn = w & 1;

    // bijective XCD swizzle (gridDim.x always a multiple of 8 here)
    const int nwg  = (int)gridDim.x;
    const int wid  = (int)blockIdx.x;
    const int swz  = (wid & 7) * (nwg >> 3) + (wid >> 3);
    const int bx   = swz & 15;          // N/128 = 16 col-blocks
    const int by   = swz >> 4;

    const int  sl    = by >> mshift;
    const long rowA0 = (long)(by & ((1 << mshift) - 1)) * 256;
    const long rowB0 = (long)bx * 128;
    const bf16_t* Ab = FUSEK ? A : (A + (long)map.a[sl] * aslab);
    const bf16_t* Wb = Bw + (long)map.w[sl] * WUNIT;
    const float*  be = bias + (long)map.w[sl] * HH;

    const int srow    = tid >> 3;                       // 0..63
    const int schunk8 = ((tid & 7) ^ (srow & 7)) * 8;   // pre-swizzled src k-offset
    const int wuni    = w * 1024;                       // wave-uniform LDS base

    const int NK = K >> 6;

    auto stage = [&](int t) {
        char* sA = lds + (t % 3) * 49152;
        char* sB = sA + 32768;
        const int k0 = t << 6;
        const bf16_t* Aeff; int ka;
        if constexpr (FUSEK) { Aeff = A + (long)(k0 >> 11) * aslab; ka = k0 & 2047; }
        else                 { Aeff = Ab; ka = k0; }
        #pragma unroll
        for (int i = 0; i < 4; ++i)
            gload_lds16(Aeff + (rowA0 + i*64 + srow) * HH + (ka + schunk8), sA + i*8192 + wuni);
        #pragma unroll
        for (int i = 0; i < 2; ++i)
            gload_lds16(Wb + (rowB0 + i*64 + srow) * (long)ldb + (k0 + schunk8), sB + i*8192 + wuni);
    };

    f32x4 acc[4][4];
    const f32x4 zero = {0.f, 0.f, 0.f, 0.f};
    #pragma unroll
    for (int i = 0; i < 4; ++i)
        #pragma unroll
        for (int j = 0; j < 4; ++j) acc[i][j] = zero;

    // prologue: K0 + K1 staged; wait K0 (6 of 12 outstanding), K1 stays in flight
    stage(0); stage(1);
    asm volatile("s_waitcnt vmcnt(6)" ::: "memory");
    __builtin_amdgcn_s_barrier();

    const int axor = (lane & 7) << 4;   // swizzle XOR for this lane's frag rows
    const int kb   = (lane >> 4) * 16;

    for (int t = 0; t < NK; ++t) {
        char* sA = lds + (t % 3) * 49152;
        char* sB = sA + 32768;
        if (t + 2 < NK) stage(t + 2);

        bf16x8 a[4][2], b[4][2];
        const int arow = wm*64 + (lane & 15);
        const int brow = wn*64 + (lane & 15);
        #pragma unroll
        for (int rf = 0; rf < 4; ++rf) {
            const int r = arow + rf*16;
            #pragma unroll
            for (int kh = 0; kh < 2; ++kh)
                a[rf][kh] = *(const bf16x8*)(sA + r*128 + ((kh*64 + kb) ^ axor));
        }
        #pragma unroll
        for (int cf = 0; cf < 4; ++cf) {
            const int r = brow + cf*16;
            #pragma unroll
            for (int kh = 0; kh < 2; ++kh)
                b[cf][kh] = *(const bf16x8*)(sB + r*128 + ((kh*64 + kb) ^ axor));
        }

        __builtin_amdgcn_s_setprio(1);
        #pragma unroll
        for (int kh = 0; kh < 2; ++kh)
            #pragma unroll
            for (int rf = 0; rf < 4; ++rf)
                #pragma unroll
                for (int cf = 0; cf < 4; ++cf)
                    acc[rf][cf] = __builtin_amdgcn_mfma_f32_16x16x32_bf16(a[rf][kh], b[cf][kh], acc[rf][cf], 0, 0, 0);
        __builtin_amdgcn_s_setprio(0);

        if (t + 2 < NK) asm volatile("s_waitcnt vmcnt(6)" ::: "memory"); // K-(t+1) landed
        else            asm volatile("s_waitcnt vmcnt(0)" ::: "memory"); // tail drain
        __builtin_amdgcn_s_barrier();
    }

    // C/D layout: col = lane&15, row = (lane>>4)*4 + reg  [m89/m91]
    const long crow0 = rowA0 + wm*64 + ((lane >> 4) * 4);
    const int  ccol0 = (int)rowB0 + wn*64 + (lane & 15);
    const long cbase = (long)sl * cslab;
    #pragma unroll
    for (int rf = 0; rf < 4; ++rf) {
        #pragma unroll
        for (int cf = 0; cf < 4; ++cf) {
            const int col = ccol0 + cf*16;
            const float bv = be[col];
            #pragma unroll
            for (int r = 0; r < 4; ++r) {
                const long row = crow0 + rf*16 + r;
                const float val = acc[rf][cf][r] + bv;
                if constexpr (OUT_F32) ((float*)Cout)[cbase + row*HH + col] = val;
                else ((bf16_t*)Cout)[cbase + row*HH + col] = __float2bfloat16(val);
            }
        }
    }
}

__global__ __launch_bounds__(256)
void f2b_kernel(const float* __restrict__ in, bf16_t* __restrict__ out, long n)
{
    long i = ((long)blockIdx.x * 256 + threadIdx.x) * 4;
    const long stride = (long)gridDim.x * 256 * 4;
    for (; i < n; i += stride) {
        const float4 v = *(const float4*)(in + i);
        __hip_bfloat162 lo, hi;
        lo.x = __float2bfloat16(v.x); lo.y = __float2bfloat16(v.y);
        hi.x = __float2bfloat16(v.z); hi.y = __float2bfloat16(v.w);
        *(__hip_bfloat162*)(out + i)     = lo;
        *(__hip_bfloat162*)(out + i + 2) = hi;
    }
}

// one wave per (v, b, head): q_len=1 attention over the 2 other views.
__global__ __launch_bounds__(256)
void attn_kernel(const bf16_t* __restrict__ q2, const bf16_t* __restrict__ k2,
                 const bf16_t* __restrict__ v2, bf16_t* __restrict__ ctx, int bshift)
{
    const long gw = (long)blockIdx.x * 4 + (threadIdx.x >> 6);
    const int lane = threadIdx.x & 63;
    const int  v_  = (int)(gw >> (bshift + 4));
    const long rem = gw & ((1L << (bshift + 4)) - 1);
    const long b   = rem >> 4;
    const int  n   = (int)(rem & 15);
    const long base = ((((long)v_ << bshift) + b)) * HH + (long)n * 128 + lane * 2;

    const __hip_bfloat162 qv = *(const __hip_bfloat162*)(q2 + base);
    const float q0 = __bfloat162float(qv.x), q1 = __bfloat162float(qv.y);
    float s[2], va[2], vb[2];
    #pragma unroll
    for (int j = 0; j < 2; ++j) {
        const long kb = ((((long)(v_*2 + j) << bshift) + b)) * HH + (long)n * 128 + lane * 2;
        const __hip_bfloat162 kv = *(const __hip_bfloat162*)(k2 + kb);
        float p = q0 * __bfloat162float(kv.x) + q1 * __bfloat162float(kv.y);
        #pragma unroll
        for (int off = 32; off > 0; off >>= 1) p += __shfl_xor(p, off);
        s[j] = p;
        const __hip_bfloat162 vv = *(const __hip_bfloat162*)(v2 + kb);
        va[j] = __bfloat162float(vv.x); vb[j] = __bfloat162float(vv.y);
    }
    const float scale = 0.08838834764831845f; // 1/sqrt(128)
    const float s0 = s[0] * scale, s1 = s[1] * scale;
    const float m  = fmaxf(s0, s1);
    const float e0 = expf(s0 - m), e1 = expf(s1 - m);
    const float inv = 1.0f / (e0 + e1);
    const float a0 = e0 * inv, a1 = e1 * inv;
    __hip_bfloat162 o;
    o.x = __float2bfloat16(a0 * va[0] + a1 * va[1]);
    o.y = __float2bfloat16(a0 * vb[0] + a1 * vb[1]);
    *(__hip_bfloat162*)(ctx + base) = o;
}

// residual (views[0] chunk) + LayerNorm, one block per row
__global__ __launch_bounds__(256)
void ln_kernel(const float* __restrict__ proj, const float* __restrict__ v0,
               const float* __restrict__ gamma, const float* __restrict__ beta,
               float* __restrict__ out)
{
    const long b = blockIdx.x;
    const int t = threadIdx.x;
    const float* pr = proj + b * HH;
    const float* vw = v0 + b * HH;
    float x[8]; float s = 0.f, s2 = 0.f;
    #pragma unroll
    for (int k = 0; k < 8; ++k) {
        const int idx = t + k * 256;
        x[k] = vw[idx] + pr[idx];
        s += x[k]; s2 += x[k] * x[k];
    }
    #pragma unroll
    for (int off = 32; off > 0; off >>= 1) { s += __shfl_xor(s, off); s2 += __shfl_xor(s2, off); }
    __shared__ float rs[4], rs2[4];
    if ((t & 63) == 0) { rs[t >> 6] = s; rs2[t >> 6] = s2; }
    __syncthreads();
    s  = rs[0] + rs[1] + rs[2] + rs[3];
    s2 = rs2[0] + rs2[1] + rs2[2] + rs2[3];
    const float mu  = s * (1.0f / 2048.0f);
    const float var = s2 * (1.0f / 2048.0f) - mu * mu;
    const float rstd = rsqrtf(var + 1e-5f);
    #pragma unroll
    for (int k = 0; k < 8; ++k) {
        const int idx = t + k * 256;
        out[b * HH + idx] = (x[k] - mu) * rstd * gamma[idx] + beta[idx];
    }
}

extern "C" void kernel_launch(void* const* d_in, const int* in_sizes, int n_in,
                              void* d_out, int out_size, void* d_ws, size_t ws_size,
                              hipStream_t stream)
{
    const float* views = (const float*)d_in[0];
    const float* Wf[8] = { (const float*)d_in[1],  (const float*)d_in[3],
                           (const float*)d_in[5],  (const float*)d_in[7],
                           (const float*)d_in[9],  (const float*)d_in[11],
                           (const float*)d_in[13], (const float*)d_in[15] };
    // Wf order: Wq, Wk, Wv, Wiq, Wik, Wiv, Wo, Wout
    const float* bq   = (const float*)d_in[2];
    const float* bk   = (const float*)d_in[4];
    const float* bv   = (const float*)d_in[6];
    const float* biq  = (const float*)d_in[8];
    const float* bik  = (const float*)d_in[10];
    const float* biv  = (const float*)d_in[12];
    const float* bo   = (const float*)d_in[14];
    const float* bout = (const float*)d_in[16];
    const float* gamma= (const float*)d_in[17];
    const float* beta = (const float*)d_in[18];

    // allow 144KB dynamic LDS (host-side, not stream-ordered: graph-capture safe)
    static bool attr_set = false;
    if (!attr_set) {
        hipFuncSetAttribute((const void*)gemm256<false,false>,
                            hipFuncAttributeMaxDynamicSharedMemorySize, LDS_TOTAL);
        hipFuncSetAttribute((const void*)gemm256<true,true>,
                            hipFuncAttributeMaxDynamicSharedMemorySize, LDS_TOTAL);
        attr_set = true;
    }

    // ---- adaptive batch chunking so the workspace footprint fits ws_size ----
    const long WBYTES = 201326592L;
    long avail = (long)ws_size - WBYTES;
    long Bc = 8192;
    while (Bc > 256 && Bc * 98304L > avail) Bc >>= 1;
    const int mshift = __builtin_ctzl((unsigned long)Bc) - 8;  // log2(Bc/256)
    const int bshift = __builtin_ctzl((unsigned long)Bc);      // log2(Bc)
    const long S1 = Bc * HH;     // elements per [Bc,H] slab

    char* ws = (char*)d_ws;
    bf16_t* WBF = (bf16_t*)ws;
    long off = WBYTES;
    bf16_t* VBF = (bf16_t*)(ws + off); off += 3*S1*2;   // views_bf -> later q2
    bf16_t* QB  = (bf16_t*)(ws + off); off += 3*S1*2;   // q -> later ctx
    bf16_t* KB  = (bf16_t*)(ws + off); off += 3*S1*2;   // k_all -> later att_out
    bf16_t* VVB = (bf16_t*)(ws + off); off += 3*S1*2;   // v_all
    bf16_t* K2  = (bf16_t*)(ws + off); long k2off = off; off += 6*S1*2;
    bf16_t* V2  = (bf16_t*)(ws + off); off += 6*S1*2;
    float*  PROJ= (float*)(ws + k2off);                 // aliases K2 (k2 consumed by attn)

    const SlabMap mp3 = {{0,1,2,0,0,0},{0,1,2,0,0,0}};
    const SlabMap mp6 = {{1,2,0,2,0,1},{0,0,1,1,2,2}};  // a = oth[v][j], w = v
    const SlabMap mp1 = {{0,0,0,0,0,0},{0,0,0,0,0,0}};

    // ---- weights f32 -> bf16, once ----
    for (int i = 0; i < 8; ++i)
        f2b_kernel<<<8192, 256, 0, stream>>>(Wf[i], WBF + (long)i * WT, WT);

    const int nwg3 = 16 * 3 * (int)(Bc >> 8);
    const int nwg6 = 16 * 6 * (int)(Bc >> 8);
    const int nwg1 = 16 * 1 * (int)(Bc >> 8);
    const int vgrid = (int)((S1 / 1024 > 8192) ? 8192 : S1 / 1024);

    for (long b0 = 0; b0 < BB; b0 += Bc) {
        for (int v = 0; v < 3; ++v)
            f2b_kernel<<<vgrid, 256, 0, stream>>>(views + v*BH + b0*HH, VBF + v*S1, S1);
        // q / k_all / v_all (batched over views)
        gemm256<false,false><<<nwg3, 512, LDS_TOTAL, stream>>>(VBF, S1, mp3, mshift, WBF + 0*WT, 2048, bq,  (void*)QB,  S1, 2048);
        gemm256<false,false><<<nwg3, 512, LDS_TOTAL, stream>>>(VBF, S1, mp3, mshift, WBF + 1*WT, 2048, bk,  (void*)KB,  S1, 2048);
        gemm256<false,false><<<nwg3, 512, LDS_TOTAL, stream>>>(VBF, S1, mp3, mshift, WBF + 2*WT, 2048, bv,  (void*)VVB, S1, 2048);
        // q2 (overwrites views_bf), k2, v2
        gemm256<false,false><<<nwg3, 512, LDS_TOTAL, stream>>>(QB,  S1, mp3, mshift, WBF + 3*WT, 2048, biq, (void*)VBF, S1, 2048);
        gemm256<false,false><<<nwg6, 512, LDS_TOTAL, stream>>>(KB,  S1, mp6, mshift, WBF + 4*WT, 2048, bik, (void*)K2,  S1, 2048);
        gemm256<false,false><<<nwg6, 512, LDS_TOTAL, stream>>>(VVB, S1, mp6, mshift, WBF + 5*WT, 2048, biv, (void*)V2,  S1, 2048);
        // attention: ctx -> QB
        attn_kernel<<<(int)(12*Bc), 256, 0, stream>>>(VBF, K2, V2, QB, bshift);
        // att_out -> KB
        gemm256<false,false><<<nwg3, 512, LDS_TOTAL, stream>>>(QB,  S1, mp3, mshift, WBF + 6*WT, 2048, bo,  (void*)KB,  S1, 2048);
        // fused projection: K=6144 batched over views' slabs of KB, f32 out (aliases K2)
        gemm256<true,true><<<nwg1, 512, LDS_TOTAL, stream>>>(KB, S1, mp1, mshift, WBF + 7*WT, 6144, bout, (void*)PROJ, 0, 6144);
        // residual + LayerNorm
        ln_kernel<<<(int)Bc, 256, 0, stream>>>(PROJ, views + b0*HH, gamma, beta, ((float*)d_out) + b0*HH);
    }
}

// Round 4
// 2422.569 us; speedup vs baseline: 1.0216x; 1.0026x over previous
//
#include <hip/hip_runtime.h>
#include <hip/hip_bf16.h>

typedef __attribute__((ext_vector_type(8))) __bf16 bf16x8;
typedef __attribute__((ext_vector_type(4))) float f32x4;
typedef __hip_bfloat16 bf16_t;

#define BB 8192L
#define HH 2048L
#define BH (8192L*2048L)      // elements per full [B,H] slab
#define WUNIT (2048L*2048L)   // elements per HxH weight unit
#define WT (3L*2048L*2048L)   // elements per [3,H,H] weight tensor (also Wout 2048x6144)
#define LDS_TOTAL 131072      // 2 K-tile buffers x (A 32KB + B 32KB)

struct SlabMap { int a[6]; int w[6]; };

__device__ __forceinline__ void gload_lds16(const void* g, void* l) {
    __builtin_amdgcn_global_load_lds((__attribute__((address_space(1))) void*)g,
                                     (__attribute__((address_space(3))) void*)l, 16, 0, 0);
}

// C[slab][M, N] = A[slab][M,K] @ W[widx][N,K]^T + bias  -- 8-phase 256x256 schedule.
// BM=BN=256, BK=64, 512 thr = 8 waves (2M x 4N), wave tile 128x64.
// LDS: 2 K-tile buffers (A 32KB + B 32KB each). Per K-tile s, 4 phases x 16 MFMA:
//   ph0: stage A(s+1)[4 ld] | read b_c0(4),a_q0(8) | mfma acc[0..3][0..1] | bar
//   ph1:                      read b_c1(4)         | mfma acc[0..3][2..3] | bar
//   ph2: stage B0(s+2)[2 ld]| read a_q1(8)         | mfma acc[4..7][0..1] | bar
//   ph3: stage B1(s+2)[2 ld]|                        mfma acc[4..7][2..3] | vmcnt(4) bar
// Race-freedom: A(s+1) -> other buffer (retired end of s-1); B(s+2) -> current buffer,
// issued after ph1/ph2 barriers (all B reads of s end at ph1). vmcnt(4) at the
// boundary leaves exactly B(s+2)'s 4 loads in flight (T4: never drain to 0 mid-loop).
// LDS rows [*][64] bf16, XOR swizzle chunk ^= row&7 (16B chunks), source pre-swizzled
// because global_load_lds writes linearly (rule 21).
template<bool OUT_F32, bool FUSEK>
__global__ __launch_bounds__(512, 1)
void gemm256(const bf16_t* __restrict__ A, long aslab, SlabMap map, int mshift,
             const bf16_t* __restrict__ Bw, int ldb,
             const float* __restrict__ bias,
             void* __restrict__ Cout, long cslab, int K)
{
    extern __shared__ char lds[];
    const int tid  = threadIdx.x;
    const int lane = tid & 63;
    const int w    = tid >> 6;
    const int wm   = w >> 2, wn = w & 3;   // 2M x 4N waves

    // bijective XCD swizzle (gridDim.x is always a multiple of 8 here)
    const int nwg = (int)gridDim.x;
    const int wid = (int)blockIdx.x;
    const int swz = (wid & 7) * (nwg >> 3) + (wid >> 3);
    const int bx  = swz & 7;               // N/256 = 8 col-blocks
    const int by  = swz >> 3;

    const int  sl    = by >> mshift;
    const long rowA0 = (long)(by & ((1 << mshift) - 1)) * 256;
    const long rowB0 = (long)bx * 256;
    const bf16_t* Ab = FUSEK ? A : (A + (long)map.a[sl] * aslab);
    const bf16_t* Wb = Bw + (long)map.w[sl] * WUNIT;
    const float*  be = bias + (long)map.w[sl] * HH;

    const int srow    = tid >> 3;                       // 0..63
    const int schunk8 = ((tid & 7) ^ (srow & 7)) * 8;   // pre-swizzled src k-offset
    const int wuni    = w * 1024;                       // wave-uniform LDS base
    const int NK = K >> 6;

    auto stageA = [&](int s) {            // both A quarters of K-tile s (4 loads)
        char* dst = lds + (s & 1) * 65536;
        const int k0 = s << 6;
        const bf16_t* Aeff; int ka;
        if constexpr (FUSEK) { Aeff = A + (long)(k0 >> 11) * aslab; ka = k0 & 2047; }
        else                 { Aeff = Ab; ka = k0; }
        #pragma unroll
        for (int i = 0; i < 4; ++i)
            gload_lds16(Aeff + (rowA0 + i*64 + srow) * HH + (ka + schunk8), dst + i*8192 + wuni);
    };
    auto stageB = [&](int s, int q) {     // one B quarter (2 loads)
        char* dst = lds + (s & 1) * 65536 + 32768 + q*16384;
        const int k0 = s << 6;
        #pragma unroll
        for (int j = 0; j < 2; ++j)
            gload_lds16(Wb + (rowB0 + q*128 + j*64 + srow) * (long)ldb + (k0 + schunk8), dst + j*8192 + wuni);
    };

    f32x4 acc[8][4];
    const f32x4 zero = {0.f, 0.f, 0.f, 0.f};
    #pragma unroll
    for (int i = 0; i < 8; ++i)
        #pragma unroll
        for (int j = 0; j < 4; ++j) acc[i][j] = zero;

    // prologue: B(0), A(0), B(1) staged; wait so B(1)'s 4 stay in flight
    stageB(0,0); stageB(0,1);
    stageA(0);
    stageB(1,0); stageB(1,1);
    asm volatile("s_waitcnt vmcnt(4)" ::: "memory");
    asm volatile("s_barrier" ::: "memory");

    const int arow16 = wm*128 + (lane & 15);     // + q*64 + rf*16
    const int brow16 = wn*64  + (lane & 15);     // + c*32 + cf*16
    const int kb     = (lane >> 4) * 16;

    #define LDSA(row, kh) (*(const bf16x8*)(bufA + (row)*128 + (((kh)*64 + kb) ^ (((row) & 7) << 4))))
    #define LDSB(row, kh) (*(const bf16x8*)(bufB + (row)*128 + (((kh)*64 + kb) ^ (((row) & 7) << 4))))

    for (int s = 0; s < NK; ++s) {
        char* bufA = lds + (s & 1) * 65536;
        char* bufB = bufA + 32768;
        bf16x8 a[4][2], b0[2][2], b1[2][2];

        // ---- ph0: q0 x c0 ----
        if (s + 1 < NK) stageA(s + 1);
        #pragma unroll
        for (int cf = 0; cf < 2; ++cf) {
            const int r = brow16 + cf*16;
            #pragma unroll
            for (int kh = 0; kh < 2; ++kh) b0[cf][kh] = LDSB(r, kh);
        }
        #pragma unroll
        for (int rf = 0; rf < 4; ++rf) {
            const int r = arow16 + rf*16;
            #pragma unroll
            for (int kh = 0; kh < 2; ++kh) a[rf][kh] = LDSA(r, kh);
        }
        __builtin_amdgcn_s_setprio(1);
        #pragma unroll
        for (int kh = 0; kh < 2; ++kh)
            #pragma unroll
            for (int rf = 0; rf < 4; ++rf)
                #pragma unroll
                for (int cf = 0; cf < 2; ++cf)
                    acc[rf][cf] = __builtin_amdgcn_mfma_f32_16x16x32_bf16(a[rf][kh], b0[cf][kh], acc[rf][cf], 0, 0, 0);
        __builtin_amdgcn_s_setprio(0);
        asm volatile("s_barrier" ::: "memory");

        // ---- ph1: q0 x c1 ----
        #pragma unroll
        for (int cf = 0; cf < 2; ++cf) {
            const int r = brow16 + 32 + cf*16;
            #pragma unroll
            for (int kh = 0; kh < 2; ++kh) b1[cf][kh] = LDSB(r, kh);
        }
        __builtin_amdgcn_s_setprio(1);
        #pragma unroll
        for (int kh = 0; kh < 2; ++kh)
            #pragma unroll
            for (int rf = 0; rf < 4; ++rf)
                #pragma unroll
                for (int cf = 0; cf < 2; ++cf)
                    acc[rf][2+cf] = __builtin_amdgcn_mfma_f32_16x16x32_bf16(a[rf][kh], b1[cf][kh], acc[rf][2+cf], 0, 0, 0);
        __builtin_amdgcn_s_setprio(0);
        asm volatile("s_barrier" ::: "memory");

        // ---- ph2: q1 x c0 ----
        if (s + 2 < NK) stageB(s + 2, 0);
        #pragma unroll
        for (int rf = 0; rf < 4; ++rf) {
            const int r = arow16 + 64 + rf*16;
            #pragma unroll
            for (int kh = 0; kh < 2; ++kh) a[rf][kh] = LDSA(r, kh);
        }
        __builtin_amdgcn_s_setprio(1);
        #pragma unroll
        for (int kh = 0; kh < 2; ++kh)
            #pragma unroll
            for (int rf = 0; rf < 4; ++rf)
                #pragma unroll
                for (int cf = 0; cf < 2; ++cf)
                    acc[4+rf][cf] = __builtin_amdgcn_mfma_f32_16x16x32_bf16(a[rf][kh], b0[cf][kh], acc[4+rf][cf], 0, 0, 0);
        __builtin_amdgcn_s_setprio(0);
        asm volatile("s_barrier" ::: "memory");

        // ---- ph3: q1 x c1 ----
        if (s + 2 < NK) stageB(s + 2, 1);
        __builtin_amdgcn_s_setprio(1);
        #pragma unroll
        for (int kh = 0; kh < 2; ++kh)
            #pragma unroll
            for (int rf = 0; rf < 4; ++rf)
                #pragma unroll
                for (int cf = 0; cf < 2; ++cf)
                    acc[4+rf][2+cf] = __builtin_amdgcn_mfma_f32_16x16x32_bf16(a[rf][kh], b1[cf][kh], acc[4+rf][2+cf], 0, 0, 0);
        __builtin_amdgcn_s_setprio(0);
        if (s + 1 < NK) {
            if (s + 2 < NK) asm volatile("s_waitcnt vmcnt(4)" ::: "memory");
            else            asm volatile("s_waitcnt vmcnt(0)" ::: "memory");
            asm volatile("s_barrier" ::: "memory");
        }
    }
    #undef LDSA
    #undef LDSB

    // C/D layout: col = lane&15, row = (lane>>4)*4 + reg  [m89/m91]
    const long crow0 = rowA0 + wm*128 + ((lane >> 4) * 4);
    const int  ccol0 = (int)rowB0 + wn*64 + (lane & 15);
    const long cbase = (long)sl * cslab;
    #pragma unroll
    for (int rf = 0; rf < 8; ++rf) {
        #pragma unroll
        for (int cf = 0; cf < 4; ++cf) {
            const int col = ccol0 + cf*16;
            const float bv = be[col];
            #pragma unroll
            for (int r = 0; r < 4; ++r) {
                const long row = crow0 + rf*16 + r;
                const float val = acc[rf][cf][r] + bv;
                if constexpr (OUT_F32) ((float*)Cout)[cbase + row*HH + col] = val;
                else ((bf16_t*)Cout)[cbase + row*HH + col] = __float2bfloat16(val);
            }
        }
    }
}

__global__ __launch_bounds__(256)
void f2b_kernel(const float* __restrict__ in, bf16_t* __restrict__ out, long n)
{
    long i = ((long)blockIdx.x * 256 + threadIdx.x) * 4;
    const long stride = (long)gridDim.x * 256 * 4;
    for (; i < n; i += stride) {
        const float4 v = *(const float4*)(in + i);
        __hip_bfloat162 lo, hi;
        lo.x = __float2bfloat16(v.x); lo.y = __float2bfloat16(v.y);
        hi.x = __float2bfloat16(v.z); hi.y = __float2bfloat16(v.w);
        *(__hip_bfloat162*)(out + i)     = lo;
        *(__hip_bfloat162*)(out + i + 2) = hi;
    }
}

// one wave per (v, b, head): q_len=1 attention over the 2 other views.
__global__ __launch_bounds__(256)
void attn_kernel(const bf16_t* __restrict__ q2, const bf16_t* __restrict__ k2,
                 const bf16_t* __restrict__ v2, bf16_t* __restrict__ ctx, int bshift)
{
    const long gw = (long)blockIdx.x * 4 + (threadIdx.x >> 6);
    const int lane = threadIdx.x & 63;
    const int  v_  = (int)(gw >> (bshift + 4));
    const long rem = gw & ((1L << (bshift + 4)) - 1);
    const long b   = rem >> 4;
    const int  n   = (int)(rem & 15);
    const long base = ((((long)v_ << bshift) + b)) * HH + (long)n * 128 + lane * 2;

    const __hip_bfloat162 qv = *(const __hip_bfloat162*)(q2 + base);
    const float q0 = __bfloat162float(qv.x), q1 = __bfloat162float(qv.y);
    float s[2], va[2], vb[2];
    #pragma unroll
    for (int j = 0; j < 2; ++j) {
        const long kb = ((((long)(v_*2 + j) << bshift) + b)) * HH + (long)n * 128 + lane * 2;
        const __hip_bfloat162 kv = *(const __hip_bfloat162*)(k2 + kb);
        float p = q0 * __bfloat162float(kv.x) + q1 * __bfloat162float(kv.y);
        #pragma unroll
        for (int off = 32; off > 0; off >>= 1) p += __shfl_xor(p, off);
        s[j] = p;
        const __hip_bfloat162 vv = *(const __hip_bfloat162*)(v2 + kb);
        va[j] = __bfloat162float(vv.x); vb[j] = __bfloat162float(vv.y);
    }
    const float scale = 0.08838834764831845f; // 1/sqrt(128)
    const float s0 = s[0] * scale, s1 = s[1] * scale;
    const float m  = fmaxf(s0, s1);
    const float e0 = expf(s0 - m), e1 = expf(s1 - m);
    const float inv = 1.0f / (e0 + e1);
    const float a0 = e0 * inv, a1 = e1 * inv;
    __hip_bfloat162 o;
    o.x = __float2bfloat16(a0 * va[0] + a1 * va[1]);
    o.y = __float2bfloat16(a0 * vb[0] + a1 * vb[1]);
    *(__hip_bfloat162*)(ctx + base) = o;
}

// residual (views[0] chunk) + LayerNorm, one block per row
__global__ __launch_bounds__(256)
void ln_kernel(const float* __restrict__ proj, const float* __restrict__ v0,
               const float* __restrict__ gamma, const float* __restrict__ beta,
               float* __restrict__ out)
{
    const long b = blockIdx.x;
    const int t = threadIdx.x;
    const float* pr = proj + b * HH;
    const float* vw = v0 + b * HH;
    float x[8]; float s = 0.f, s2 = 0.f;
    #pragma unroll
    for (int k = 0; k < 8; ++k) {
        const int idx = t + k * 256;
        x[k] = vw[idx] + pr[idx];
        s += x[k]; s2 += x[k] * x[k];
    }
    #pragma unroll
    for (int off = 32; off > 0; off >>= 1) { s += __shfl_xor(s, off); s2 += __shfl_xor(s2, off); }
    __shared__ float rs[4], rs2[4];
    if ((t & 63) == 0) { rs[t >> 6] = s; rs2[t >> 6] = s2; }
    __syncthreads();
    s  = rs[0] + rs[1] + rs[2] + rs[3];
    s2 = rs2[0] + rs2[1] + rs2[2] + rs2[3];
    const float mu  = s * (1.0f / 2048.0f);
    const float var = s2 * (1.0f / 2048.0f) - mu * mu;
    const float rstd = rsqrtf(var + 1e-5f);
    #pragma unroll
    for (int k = 0; k < 8; ++k) {
        const int idx = t + k * 256;
        out[b * HH + idx] = (x[k] - mu) * rstd * gamma[idx] + beta[idx];
    }
}

extern "C" void kernel_launch(void* const* d_in, const int* in_sizes, int n_in,
                              void* d_out, int out_size, void* d_ws, size_t ws_size,
                              hipStream_t stream)
{
    const float* views = (const float*)d_in[0];
    const float* Wf[8] = { (const float*)d_in[1],  (const float*)d_in[3],
                           (const float*)d_in[5],  (const float*)d_in[7],
                           (const float*)d_in[9],  (const float*)d_in[11],
                           (const float*)d_in[13], (const float*)d_in[15] };
    // Wf order: Wq, Wk, Wv, Wiq, Wik, Wiv, Wo, Wout
    const float* bq   = (const float*)d_in[2];
    const float* bk   = (const float*)d_in[4];
    const float* bv   = (const float*)d_in[6];
    const float* biq  = (const float*)d_in[8];
    const float* bik  = (const float*)d_in[10];
    const float* biv  = (const float*)d_in[12];
    const float* bo   = (const float*)d_in[14];
    const float* bout = (const float*)d_in[16];
    const float* gamma= (const float*)d_in[17];
    const float* beta = (const float*)d_in[18];

    static bool attr_set = false;
    if (!attr_set) {
        hipFuncSetAttribute((const void*)gemm256<false,false>,
                            hipFuncAttributeMaxDynamicSharedMemorySize, LDS_TOTAL);
        hipFuncSetAttribute((const void*)gemm256<true,true>,
                            hipFuncAttributeMaxDynamicSharedMemorySize, LDS_TOTAL);
        attr_set = true;
    }

    // ---- adaptive batch chunking so the workspace footprint fits ws_size ----
    const long WBYTES = 201326592L;
    long avail = (long)ws_size - WBYTES;
    long Bc = 8192;
    while (Bc > 256 && Bc * 98304L > avail) Bc >>= 1;
    const int mshift = __builtin_ctzl((unsigned long)Bc) - 8;  // log2(Bc/256)
    const int bshift = __builtin_ctzl((unsigned long)Bc);      // log2(Bc)
    const long S1 = Bc * HH;     // elements per [Bc,H] slab

    char* ws = (char*)d_ws;
    bf16_t* WBF = (bf16_t*)ws;
    long off = WBYTES;
    bf16_t* VBF = (bf16_t*)(ws + off); off += 3*S1*2;   // views_bf -> later q2
    bf16_t* QB  = (bf16_t*)(ws + off); off += 3*S1*2;   // q -> later ctx
    bf16_t* KB  = (bf16_t*)(ws + off); off += 3*S1*2;   // k_all -> later att_out
    bf16_t* VVB = (bf16_t*)(ws + off); off += 3*S1*2;   // v_all
    bf16_t* K2  = (bf16_t*)(ws + off); long k2off = off; off += 6*S1*2;
    bf16_t* V2  = (bf16_t*)(ws + off); off += 6*S1*2;
    float*  PROJ= (float*)(ws + k2off);                 // aliases K2 (k2 consumed by attn)

    const SlabMap mp3 = {{0,1,2,0,0,0},{0,1,2,0,0,0}};
    const SlabMap mp6 = {{1,2,0,2,0,1},{0,0,1,1,2,2}};  // a = oth[v][j], w = v
    const SlabMap mp1 = {{0,0,0,0,0,0},{0,0,0,0,0,0}};

    // ---- weights f32 -> bf16, once ----
    for (int i = 0; i < 8; ++i)
        f2b_kernel<<<8192, 256, 0, stream>>>(Wf[i], WBF + (long)i * WT, WT);

    const int nwg3 = 8 * 3 * (int)(Bc >> 8);
    const int nwg6 = 8 * 6 * (int)(Bc >> 8);
    const int nwg1 = 8 * 1 * (int)(Bc >> 8);
    const int vgrid = (int)((S1 / 1024 > 8192) ? 8192 : S1 / 1024);

    for (long b0 = 0; b0 < BB; b0 += Bc) {
        for (int v = 0; v < 3; ++v)
            f2b_kernel<<<vgrid, 256, 0, stream>>>(views + v*BH + b0*HH, VBF + v*S1, S1);
        // q / k_all / v_all (batched over views)
        gemm256<false,false><<<nwg3, 512, LDS_TOTAL, stream>>>(VBF, S1, mp3, mshift, WBF + 0*WT, 2048, bq,  (void*)QB,  S1, 2048);
        gemm256<false,false><<<nwg3, 512, LDS_TOTAL, stream>>>(VBF, S1, mp3, mshift, WBF + 1*WT, 2048, bk,  (void*)KB,  S1, 2048);
        gemm256<false,false><<<nwg3, 512, LDS_TOTAL, stream>>>(VBF, S1, mp3, mshift, WBF + 2*WT, 2048, bv,  (void*)VVB, S1, 2048);
        // q2 (overwrites views_bf), k2, v2
        gemm256<false,false><<<nwg3, 512, LDS_TOTAL, stream>>>(QB,  S1, mp3, mshift, WBF + 3*WT, 2048, biq, (void*)VBF, S1, 2048);
        gemm256<false,false><<<nwg6, 512, LDS_TOTAL, stream>>>(KB,  S1, mp6, mshift, WBF + 4*WT, 2048, bik, (void*)K2,  S1, 2048);
        gemm256<false,false><<<nwg6, 512, LDS_TOTAL, stream>>>(VVB, S1, mp6, mshift, WBF + 5*WT, 2048, biv, (void*)V2,  S1, 2048);
        // attention: ctx -> QB
        attn_kernel<<<(int)(12*Bc), 256, 0, stream>>>(VBF, K2, V2, QB, bshift);
        // att_out -> KB
        gemm256<false,false><<<nwg3, 512, LDS_TOTAL, stream>>>(QB,  S1, mp3, mshift, WBF + 6*WT, 2048, bo,  (void*)KB,  S1, 2048);
        // fused projection: K=6144 batched over views' slabs of KB, f32 out (aliases K2)
        gemm256<true,true><<<nwg1, 512, LDS_TOTAL, stream>>>(KB, S1, mp1, mshift, WBF + 7*WT, 6144, bout, (void*)PROJ, 0, 6144);
        // residual + LayerNorm
        ln_kernel<<<(int)Bc, 256, 0, stream>>>(PROJ, views + b0*HH, gamma, beta, ((float*)d_out) + b0*HH);
    }
}

// Round 5
// 1980.125 us; speedup vs baseline: 1.2499x; 1.2234x over previous
//
#include <hip/hip_runtime.h>
#include <hip/hip_bf16.h>

typedef __attribute__((ext_vector_type(8))) __bf16 bf16x8;
typedef __attribute__((ext_vector_type(4))) float f32x4;
typedef __hip_bfloat16 bf16_t;

#define BB 8192L
#define HH 2048L
#define BH (8192L*2048L)      // elements per full [B,H] slab
#define WUNIT (2048L*2048L)   // elements per HxH weight unit
#define WT (3L*2048L*2048L)   // elements per [3,H,H] weight tensor
#define LDS_TOTAL 131072      // 2 K-tile buffers x (A 32KB + B 32KB)

struct SlabMap { int a[6]; int w[6]; };

__device__ __forceinline__ void gload_lds16(const void* g, void* l) {
    __builtin_amdgcn_global_load_lds((__attribute__((address_space(1))) void*)g,
                                     (__attribute__((address_space(3))) void*)l, 16, 0, 0);
}

// C[slab][M, N=2048] = A[slab][M,K] @ W[widx][N,K]^T (+ bias)  -- 8-phase 256x256.
// BM=BN=256, BK=64, 512 thr = 8 waves (2M x 4N), wave tile 128x64.
// Per K-tile s, 4 phases x 16 MFMA; A(s+1) staged at ph0 (other buffer),
// B(s+2) quarters staged at ph2/ph3 into CURRENT buffer (its B-reads ended at ph1).
// Boundary wait vmcnt(4): only B(s+2)'s 4 loads stay in flight (T4, never 0 mid-loop).
// LDS rows [*][64] bf16, XOR swizzle chunk ^= row&7, source pre-swizzled (rule 21).
template<bool OUT_F32, bool FUSEK>
__global__ __launch_bounds__(512, 1)
void gemm256(const bf16_t* __restrict__ A, int lda, long aslab, SlabMap map, int mshift,
             const bf16_t* __restrict__ Bw, int ldb,
             const float* __restrict__ bias,
             void* __restrict__ Cout, int ldc, long cslab, int K)
{
    extern __shared__ char lds[];
    const int tid  = threadIdx.x;
    const int lane = tid & 63;
    const int w    = tid >> 6;
    const int wm   = w >> 2, wn = w & 3;   // 2M x 4N waves

    // bijective XCD swizzle (gridDim.x is always a multiple of 8 here)
    const int nwg = (int)gridDim.x;
    const int wid = (int)blockIdx.x;
    const int swz = (wid & 7) * (nwg >> 3) + (wid >> 3);
    const int bx  = swz & 7;               // N=2048 -> 8 col-blocks
    const int by  = swz >> 3;

    const int  sl    = by >> mshift;
    const long rowA0 = (long)(by & ((1 << mshift) - 1)) * 256;
    const long rowB0 = (long)bx * 256;
    const bf16_t* Ab = FUSEK ? A : (A + (long)map.a[sl] * aslab);
    const bf16_t* Wb = Bw + (long)map.w[sl] * WUNIT;
    const float*  be = bias ? (bias + (long)map.w[sl] * HH) : nullptr;

    const int srow    = tid >> 3;                       // 0..63
    const int schunk8 = ((tid & 7) ^ (srow & 7)) * 8;   // pre-swizzled src k-offset
    const int wuni    = w * 1024;                       // wave-uniform LDS base
    const int NK = K >> 6;

    auto stageA = [&](int s) {            // both A quarters of K-tile s (4 loads)
        char* dst = lds + (s & 1) * 65536;
        const int k0 = s << 6;
        const bf16_t* Aeff; int ka;
        if constexpr (FUSEK) { Aeff = A + (long)(k0 >> 11) * aslab; ka = k0 & 2047; }
        else                 { Aeff = Ab; ka = k0; }
        #pragma unroll
        for (int i = 0; i < 4; ++i)
            gload_lds16(Aeff + (rowA0 + i*64 + srow) * (long)lda + (ka + schunk8), dst + i*8192 + wuni);
    };
    auto stageB = [&](int s, int q) {     // one B quarter (2 loads)
        char* dst = lds + (s & 1) * 65536 + 32768 + q*16384;
        const int k0 = s << 6;
        #pragma unroll
        for (int j = 0; j < 2; ++j)
            gload_lds16(Wb + (rowB0 + q*128 + j*64 + srow) * (long)ldb + (k0 + schunk8), dst + j*8192 + wuni);
    };

    f32x4 acc[8][4];
    const f32x4 zero = {0.f, 0.f, 0.f, 0.f};
    #pragma unroll
    for (int i = 0; i < 8; ++i)
        #pragma unroll
        for (int j = 0; j < 4; ++j) acc[i][j] = zero;

    stageB(0,0); stageB(0,1);
    stageA(0);
    stageB(1,0); stageB(1,1);
    asm volatile("s_waitcnt vmcnt(4)" ::: "memory");
    asm volatile("s_barrier" ::: "memory");

    const int arow16 = wm*128 + (lane & 15);
    const int brow16 = wn*64  + (lane & 15);
    const int kb     = (lane >> 4) * 16;

    #define LDSA(row, kh) (*(const bf16x8*)(bufA + (row)*128 + (((kh)*64 + kb) ^ (((row) & 7) << 4))))
    #define LDSB(row, kh) (*(const bf16x8*)(bufB + (row)*128 + (((kh)*64 + kb) ^ (((row) & 7) << 4))))

    for (int s = 0; s < NK; ++s) {
        char* bufA = lds + (s & 1) * 65536;
        char* bufB = bufA + 32768;
        bf16x8 a[4][2], b0[2][2], b1[2][2];

        // ---- ph0: q0 x c0 ----
        if (s + 1 < NK) stageA(s + 1);
        #pragma unroll
        for (int cf = 0; cf < 2; ++cf) {
            const int r = brow16 + cf*16;
            #pragma unroll
            for (int kh = 0; kh < 2; ++kh) b0[cf][kh] = LDSB(r, kh);
        }
        #pragma unroll
        for (int rf = 0; rf < 4; ++rf) {
            const int r = arow16 + rf*16;
            #pragma unroll
            for (int kh = 0; kh < 2; ++kh) a[rf][kh] = LDSA(r, kh);
        }
        __builtin_amdgcn_s_setprio(1);
        #pragma unroll
        for (int kh = 0; kh < 2; ++kh)
            #pragma unroll
            for (int rf = 0; rf < 4; ++rf)
                #pragma unroll
                for (int cf = 0; cf < 2; ++cf)
                    acc[rf][cf] = __builtin_amdgcn_mfma_f32_16x16x32_bf16(a[rf][kh], b0[cf][kh], acc[rf][cf], 0, 0, 0);
        __builtin_amdgcn_s_setprio(0);
        asm volatile("s_barrier" ::: "memory");

        // ---- ph1: q0 x c1 ----
        #pragma unroll
        for (int cf = 0; cf < 2; ++cf) {
            const int r = brow16 + 32 + cf*16;
            #pragma unroll
            for (int kh = 0; kh < 2; ++kh) b1[cf][kh] = LDSB(r, kh);
        }
        __builtin_amdgcn_s_setprio(1);
        #pragma unroll
        for (int kh = 0; kh < 2; ++kh)
            #pragma unroll
            for (int rf = 0; rf < 4; ++rf)
                #pragma unroll
                for (int cf = 0; cf < 2; ++cf)
                    acc[rf][2+cf] = __builtin_amdgcn_mfma_f32_16x16x32_bf16(a[rf][kh], b1[cf][kh], acc[rf][2+cf], 0, 0, 0);
        __builtin_amdgcn_s_setprio(0);
        asm volatile("s_barrier" ::: "memory");

        // ---- ph2: q1 x c0 ----
        if (s + 2 < NK) stageB(s + 2, 0);
        #pragma unroll
        for (int rf = 0; rf < 4; ++rf) {
            const int r = arow16 + 64 + rf*16;
            #pragma unroll
            for (int kh = 0; kh < 2; ++kh) a[rf][kh] = LDSA(r, kh);
        }
        __builtin_amdgcn_s_setprio(1);
        #pragma unroll
        for (int kh = 0; kh < 2; ++kh)
            #pragma unroll
            for (int rf = 0; rf < 4; ++rf)
                #pragma unroll
                for (int cf = 0; cf < 2; ++cf)
                    acc[4+rf][cf] = __builtin_amdgcn_mfma_f32_16x16x32_bf16(a[rf][kh], b0[cf][kh], acc[4+rf][cf], 0, 0, 0);
        __builtin_amdgcn_s_setprio(0);
        asm volatile("s_barrier" ::: "memory");

        // ---- ph3: q1 x c1 ----
        if (s + 2 < NK) stageB(s + 2, 1);
        __builtin_amdgcn_s_setprio(1);
        #pragma unroll
        for (int kh = 0; kh < 2; ++kh)
            #pragma unroll
            for (int rf = 0; rf < 4; ++rf)
                #pragma unroll
                for (int cf = 0; cf < 2; ++cf)
                    acc[4+rf][2+cf] = __builtin_amdgcn_mfma_f32_16x16x32_bf16(a[rf][kh], b1[cf][kh], acc[4+rf][2+cf], 0, 0, 0);
        __builtin_amdgcn_s_setprio(0);
        if (s + 1 < NK) {
            if (s + 2 < NK) asm volatile("s_waitcnt vmcnt(4)" ::: "memory");
            else            asm volatile("s_waitcnt vmcnt(0)" ::: "memory");
            asm volatile("s_barrier" ::: "memory");
        }
    }
    #undef LDSA
    #undef LDSB

    // C/D layout: col = lane&15, row = (lane>>4)*4 + reg  [m89/m91]
    const long crow0 = rowA0 + wm*128 + ((lane >> 4) * 4);
    const int  ccol0 = (int)rowB0 + wn*64 + (lane & 15);
    const long cbase = (long)sl * cslab;
    #pragma unroll
    for (int rf = 0; rf < 8; ++rf) {
        #pragma unroll
        for (int cf = 0; cf < 4; ++cf) {
            const int col = ccol0 + cf*16;
            const float bv = be ? be[col] : 0.f;
            #pragma unroll
            for (int r = 0; r < 4; ++r) {
                const long row = crow0 + rf*16 + r;
                const float val = acc[rf][cf][r] + bv;
                if constexpr (OUT_F32) ((float*)Cout)[cbase + row*(long)ldc + col] = val;
                else ((bf16_t*)Cout)[cbase + row*(long)ldc + col] = __float2bfloat16(val);
            }
        }
    }
}

__global__ __launch_bounds__(256)
void f2b_kernel(const float* __restrict__ in, bf16_t* __restrict__ out, long n)
{
    long i = ((long)blockIdx.x * 256 + threadIdx.x) * 4;
    const long stride = (long)gridDim.x * 256 * 4;
    for (; i < n; i += stride) {
        const float4 v = *(const float4*)(in + i);
        __hip_bfloat162 lo, hi;
        lo.x = __float2bfloat16(v.x); lo.y = __float2bfloat16(v.y);
        hi.x = __float2bfloat16(v.z); hi.y = __float2bfloat16(v.w);
        *(__hip_bfloat162*)(out + i)     = lo;
        *(__hip_bfloat162*)(out + i + 2) = hi;
    }
}

// transpose-convert: out[mat][c][r] = (bf16) in[mat][r][c], mats are 2048x2048
__global__ __launch_bounds__(256)
void f2bT_kernel(const float* __restrict__ in, bf16_t* __restrict__ out)
{
    __shared__ float sm[64][65];
    const int tile = blockIdx.x;
    const int mat  = tile >> 10;
    const int tr   = (tile >> 5) & 31, tc = tile & 31;
    const int lr = threadIdx.x >> 4;
    const int lc = (threadIdx.x & 15) * 4;
    const float* src = in + (long)mat*WUNIT + ((long)tr*64)*2048 + tc*64;
    #pragma unroll
    for (int it = 0; it < 4; ++it) {
        const int r = lr + it*16;
        const float4 v = *(const float4*)(src + (long)r*2048 + lc);
        sm[r][lc] = v.x; sm[r][lc+1] = v.y; sm[r][lc+2] = v.z; sm[r][lc+3] = v.w;
    }
    __syncthreads();
    bf16_t* dst = out + (long)mat*WUNIT + ((long)tc*64)*2048 + tr*64;
    #pragma unroll
    for (int it = 0; it < 4; ++it) {
        const int r = lr + it*16;
        __hip_bfloat162 p0, p1;
        p0.x = __float2bfloat16(sm[lc+0][r]); p0.y = __float2bfloat16(sm[lc+1][r]);
        p1.x = __float2bfloat16(sm[lc+2][r]); p1.y = __float2bfloat16(sm[lc+3][r]);
        *(__hip_bfloat162*)(dst + (long)r*2048 + lc)     = p0;
        *(__hip_bfloat162*)(dst + (long)r*2048 + lc + 2) = p1;
    }
}

// out[g2] = sum_k W2[g2*ld+k]*b1[k] + badd[g2]   (f32, exact bias fold)
__global__ __launch_bounds__(256)
void biasfold_kernel(const float* __restrict__ W2, int ld,
                     const float* __restrict__ b1, const float* __restrict__ badd,
                     float* __restrict__ out, int K)
{
    const int g2 = blockIdx.x;
    const int t  = threadIdx.x;
    float s = 0.f;
    for (int k = t; k < K; k += 256) s += W2[(long)g2*ld + k] * b1[k];
    #pragma unroll
    for (int off = 32; off > 0; off >>= 1) s += __shfl_xor(s, off);
    __shared__ float rs[4];
    if ((t & 63) == 0) rs[t >> 6] = s;
    __syncthreads();
    if (t == 0) out[g2] = rs[0] + rs[1] + rs[2] + rs[3] + badd[g2];
}

// one wave per (v, b, head): q_len=1 attention over the 2 other views.
__global__ __launch_bounds__(256)
void attn_kernel(const bf16_t* __restrict__ q2, const bf16_t* __restrict__ k2,
                 const bf16_t* __restrict__ v2, bf16_t* __restrict__ ctx, int bshift)
{
    const long gw = (long)blockIdx.x * 4 + (threadIdx.x >> 6);
    const int lane = threadIdx.x & 63;
    const int  v_  = (int)(gw >> (bshift + 4));
    const long rem = gw & ((1L << (bshift + 4)) - 1);
    const long b   = rem >> 4;
    const int  n   = (int)(rem & 15);
    const long base = ((((long)v_ << bshift) + b)) * HH + (long)n * 128 + lane * 2;

    const __hip_bfloat162 qv = *(const __hip_bfloat162*)(q2 + base);
    const float q0 = __bfloat162float(qv.x), q1 = __bfloat162float(qv.y);
    float s[2], va[2], vb[2];
    #pragma unroll
    for (int j = 0; j < 2; ++j) {
        const long kb = ((((long)(v_*2 + j) << bshift) + b)) * HH + (long)n * 128 + lane * 2;
        const __hip_bfloat162 kv = *(const __hip_bfloat162*)(k2 + kb);
        float p = q0 * __bfloat162float(kv.x) + q1 * __bfloat162float(kv.y);
        #pragma unroll
        for (int off = 32; off > 0; off >>= 1) p += __shfl_xor(p, off);
        s[j] = p;
        const __hip_bfloat162 vv = *(const __hip_bfloat162*)(v2 + kb);
        va[j] = __bfloat162float(vv.x); vb[j] = __bfloat162float(vv.y);
    }
    const float scale = 0.08838834764831845f; // 1/sqrt(128)
    const float s0 = s[0] * scale, s1 = s[1] * scale;
    const float m  = fmaxf(s0, s1);
    const float e0 = expf(s0 - m), e1 = expf(s1 - m);
    const float inv = 1.0f / (e0 + e1);
    const float a0 = e0 * inv, a1 = e1 * inv;
    __hip_bfloat162 o;
    o.x = __float2bfloat16(a0 * va[0] + a1 * va[1]);
    o.y = __float2bfloat16(a0 * vb[0] + a1 * vb[1]);
    *(__hip_bfloat162*)(ctx + base) = o;
}

// residual (views[0] chunk) + LayerNorm, one block per row
__global__ __launch_bounds__(256)
void ln_kernel(const float* __restrict__ proj, const float* __restrict__ v0,
               const float* __restrict__ gamma, const float* __restrict__ beta,
               float* __restrict__ out)
{
    const long b = blockIdx.x;
    const int t = threadIdx.x;
    const float* pr = proj + b * HH;
    const float* vw = v0 + b * HH;
    float x[8]; float s = 0.f, s2 = 0.f;
    #pragma unroll
    for (int k = 0; k < 8; ++k) {
        const int idx = t + k * 256;
        x[k] = vw[idx] + pr[idx];
        s += x[k]; s2 += x[k] * x[k];
    }
    #pragma unroll
    for (int off = 32; off > 0; off >>= 1) { s += __shfl_xor(s, off); s2 += __shfl_xor(s2, off); }
    __shared__ float rs[4], rs2[4];
    if ((t & 63) == 0) { rs[t >> 6] = s; rs2[t >> 6] = s2; }
    __syncthreads();
    s  = rs[0] + rs[1] + rs[2] + rs[3];
    s2 = rs2[0] + rs2[1] + rs2[2] + rs2[3];
    const float mu  = s * (1.0f / 2048.0f);
    const float var = s2 * (1.0f / 2048.0f) - mu * mu;
    const float rstd = rsqrtf(var + 1e-5f);
    #pragma unroll
    for (int k = 0; k < 8; ++k) {
        const int idx = t + k * 256;
        out[b * HH + idx] = (x[k] - mu) * rstd * gamma[idx] + beta[idx];
    }
}

extern "C" void kernel_launch(void* const* d_in, const int* in_sizes, int n_in,
                              void* d_out, int out_size, void* d_ws, size_t ws_size,
                              hipStream_t stream)
{
    const float* views = (const float*)d_in[0];
    const float* Wq   = (const float*)d_in[1];  const float* bq   = (const float*)d_in[2];
    const float* Wk   = (const float*)d_in[3];  const float* bk   = (const float*)d_in[4];
    const float* Wv   = (const float*)d_in[5];  const float* bv   = (const float*)d_in[6];
    const float* Wiq  = (const float*)d_in[7];  const float* biq  = (const float*)d_in[8];
    const float* Wik  = (const float*)d_in[9];  const float* bik  = (const float*)d_in[10];
    const float* Wiv  = (const float*)d_in[11]; const float* biv  = (const float*)d_in[12];
    const float* Wo   = (const float*)d_in[13]; const float* bo   = (const float*)d_in[14];
    const float* Wout = (const float*)d_in[15]; const float* bout = (const float*)d_in[16];
    const float* gamma= (const float*)d_in[17]; const float* beta = (const float*)d_in[18];

    static bool attr_set = false;
    if (!attr_set) {
        hipFuncSetAttribute((const void*)gemm256<false,false>,
                            hipFuncAttributeMaxDynamicSharedMemorySize, LDS_TOTAL);
        hipFuncSetAttribute((const void*)gemm256<true,true>,
                            hipFuncAttributeMaxDynamicSharedMemorySize, LDS_TOTAL);
        attr_set = true;
    }

    // ---- workspace layout ----
    // weights: 24 units originals (12 normal + 12 transposed) + 18 units folded + biases
    char* ws = (char*)d_ws;
    bf16_t* WIQ   = (bf16_t*)ws;                 // 3u  (A of q-fold)
    bf16_t* WIK   = WIQ  + 3*WUNIT;              // 3u
    bf16_t* WIV   = WIK  + 3*WUNIT;              // 3u
    bf16_t* WOUTB = WIV  + 3*WUNIT;              // 3u  (Wout bf16, A of fin-fold)
    bf16_t* WQT   = WOUTB+ 3*WUNIT;              // 3u  transposed
    bf16_t* WKT   = WQT  + 3*WUNIT;              // 3u
    bf16_t* WVT   = WKT  + 3*WUNIT;              // 3u
    bf16_t* WOT   = WVT  + 3*WUNIT;              // 3u
    bf16_t* WQ2   = WOT  + 3*WUNIT;              // 3u  folded
    bf16_t* WK2   = WQ2  + 3*WUNIT;              // 6u
    bf16_t* WV2   = WK2  + 6*WUNIT;              // 6u
    bf16_t* WFIN  = WV2  + 6*WUNIT;              // 3u  as [2048][6144]
    float*  BQ2   = (float*)(WFIN + 3*WUNIT);    // 3*2048
    float*  BK2   = BQ2 + 3*HH;                  // 6*2048
    float*  BV2   = BK2 + 6*HH;                  // 6*2048
    float*  BFIN  = BV2 + 6*HH;                  // 2048
    const long WBYTES_ALL = 42L*WUNIT*2 + 16L*HH*4;

    // ---- adaptive batch chunking: activations = 18 slabs x Bc*2048*2B ----
    long avail = (long)ws_size - WBYTES_ALL;
    long Bc = 8192;
    while (Bc > 256 && Bc * 73728L > avail) Bc >>= 1;
    const int mshift = __builtin_ctzl((unsigned long)Bc) - 8;  // log2(Bc/256)
    const int bshift = __builtin_ctzl((unsigned long)Bc);      // log2(Bc)
    const long S1 = Bc * HH;

    char* act = ws + WBYTES_ALL;
    bf16_t* VBF = (bf16_t*)act;          // views bf16 -> later ctx (3 slabs)
    bf16_t* Q2B = VBF + 3*S1;            // q2 (3)
    bf16_t* K2  = Q2B + 3*S1;            // k2 (6)
    bf16_t* V2  = K2  + 6*S1;            // v2 (6)
    float*  PROJ= (float*)K2;            // aliases K2 (dead after attn)

    const SlabMap mp3  = {{0,1,2,0,0,0},{0,1,2,0,0,0}};
    const SlabMap mp6k = {{1,2,0,2,0,1},{0,1,2,3,4,5}};  // a = oth[v][j], w = pair idx
    const SlabMap mpfk = {{0,0,1,1,2,2},{1,2,0,2,0,1}};  // fold: A=Wi*[v], W=W*T[oth]
    const SlabMap mp1  = {{0,0,0,0,0,0},{0,0,0,0,0,0}};
    const int oth[3][2] = {{1,2},{0,2},{0,1}};

    // ---- one-time: weight conversions ----
    f2b_kernel<<<4096, 256, 0, stream>>>(Wiq,  WIQ,   WT);
    f2b_kernel<<<4096, 256, 0, stream>>>(Wik,  WIK,   WT);
    f2b_kernel<<<4096, 256, 0, stream>>>(Wiv,  WIV,   WT);
    f2b_kernel<<<4096, 256, 0, stream>>>(Wout, WOUTB, WT);
    f2bT_kernel<<<3072, 256, 0, stream>>>(Wq, WQT);
    f2bT_kernel<<<3072, 256, 0, stream>>>(Wk, WKT);
    f2bT_kernel<<<3072, 256, 0, stream>>>(Wv, WVT);
    f2bT_kernel<<<3072, 256, 0, stream>>>(Wo, WOT);

    // ---- one-time: weight folds (M=2048 -> mshift=3) ----
    gemm256<false,false><<<192, 512, LDS_TOTAL, stream>>>(WIQ, 2048, WUNIT, mp3,  3, WQT, 2048, nullptr, (void*)WQ2, 2048, WUNIT, 2048);
    gemm256<false,false><<<384, 512, LDS_TOTAL, stream>>>(WIK, 2048, WUNIT, mpfk, 3, WKT, 2048, nullptr, (void*)WK2, 2048, WUNIT, 2048);
    gemm256<false,false><<<384, 512, LDS_TOTAL, stream>>>(WIV, 2048, WUNIT, mpfk, 3, WVT, 2048, nullptr, (void*)WV2, 2048, WUNIT, 2048);
    gemm256<false,false><<<192, 512, LDS_TOTAL, stream>>>(WOUTB, 6144, 2048, mp3, 3, WOT, 2048, nullptr, (void*)WFIN, 6144, 2048, 2048);

    // ---- one-time: exact bias folds (f32) ----
    for (int v = 0; v < 3; ++v)
        biasfold_kernel<<<2048, 256, 0, stream>>>(Wiq + (long)v*WUNIT, 2048, bq + v*HH, biq + v*HH, BQ2 + v*HH, 2048);
    for (int v = 0; v < 3; ++v)
        for (int j = 0; j < 2; ++j) {
            const int p = v*2 + j, o = oth[v][j];
            biasfold_kernel<<<2048, 256, 0, stream>>>(Wik + (long)v*WUNIT, 2048, bk + o*HH, bik + v*HH, BK2 + p*HH, 2048);
            biasfold_kernel<<<2048, 256, 0, stream>>>(Wiv + (long)v*WUNIT, 2048, bv + o*HH, biv + v*HH, BV2 + p*HH, 2048);
        }
    biasfold_kernel<<<2048, 256, 0, stream>>>(Wout, 6144, bo, bout, BFIN, 6144);

    const int nwg3 = 8 * 3 * (int)(Bc >> 8);
    const int nwg6 = 8 * 6 * (int)(Bc >> 8);
    const int nwg1 = 8 * 1 * (int)(Bc >> 8);
    const int vgrid = (int)((S1 / 1024 > 8192) ? 8192 : S1 / 1024);

    for (long b0 = 0; b0 < BB; b0 += Bc) {
        for (int v = 0; v < 3; ++v)
            f2b_kernel<<<vgrid, 256, 0, stream>>>(views + v*BH + b0*HH, VBF + v*S1, S1);
        // q2 / k2 / v2 directly from views via folded weights
        gemm256<false,false><<<nwg3, 512, LDS_TOTAL, stream>>>(VBF, 2048, S1, mp3,  mshift, WQ2, 2048, BQ2, (void*)Q2B, 2048, S1, 2048);
        gemm256<false,false><<<nwg6, 512, LDS_TOTAL, stream>>>(VBF, 2048, S1, mp6k, mshift, WK2, 2048, BK2, (void*)K2,  2048, S1, 2048);
        gemm256<false,false><<<nwg6, 512, LDS_TOTAL, stream>>>(VBF, 2048, S1, mp6k, mshift, WV2, 2048, BV2, (void*)V2,  2048, S1, 2048);
        // attention: ctx -> VBF (views dead)
        attn_kernel<<<(int)(12*Bc), 256, 0, stream>>>(Q2B, K2, V2, VBF, bshift);
        // fused projection: proj = sum_v ctx[v] @ WFIN_v^T + BFIN (K=6144 over ctx slabs)
        gemm256<true,true><<<nwg1, 512, LDS_TOTAL, stream>>>(VBF, 2048, S1, mp1, mshift, WFIN, 6144, BFIN, (void*)PROJ, 2048, 0, 6144);
        // residual + LayerNorm
        ln_kernel<<<(int)Bc, 256, 0, stream>>>(PROJ, views + b0*HH, gamma, beta, ((float*)d_out) + b0*HH);
    }
}

// Round 6
// 1698.858 us; speedup vs baseline: 1.4568x; 1.1656x over previous
//
#include <hip/hip_runtime.h>
#include <hip/hip_bf16.h>

typedef __attribute__((ext_vector_type(8))) __bf16 bf16x8;
typedef __attribute__((ext_vector_type(4))) float f32x4;
typedef __hip_bfloat16 bf16_t;

#define BB 8192L
#define HH 2048L
#define BH (8192L*2048L)      // elements per full [B,H] slab
#define WUNIT (2048L*2048L)   // elements per HxH weight unit
#define WT (3L*2048L*2048L)   // elements per [3,H,H] weight tensor
#define LDS_TOTAL 131072      // 2 K-tile buffers x (A 32KB + B 32KB)

struct SlabMap { int a[6]; int w[6]; };
struct Ptrs4 { const float* in[4]; bf16_t* out[4]; };
struct FoldJob { const float* W2; const float* b1; const float* badd; float* out; int ld; };
struct FoldPack { FoldJob j[16]; };

__device__ __forceinline__ void gload_lds16(const void* g, void* l) {
    __builtin_amdgcn_global_load_lds((__attribute__((address_space(1))) void*)g,
                                     (__attribute__((address_space(3))) void*)l, 16, 0, 0);
}

// C[slab][M, N=2048] = A[slab][M,K] @ W[widx][N,K]^T (+ bias)  -- 8-phase 256x256.
// BM=BN=256, BK=64, 512 thr = 8 waves (2M x 4N), wave tile 128x64.
// Phase order (m201 pattern): {stage; ds_read frags; s_barrier; sched_barrier;
// MFMA cluster} -- the LDS-read drain folds into the barrier wait instead of
// stalling inside the compute stretch. Race audit under this ordering:
//  - b0 reads retire before each wave's ph0-MFMA issue < ph1 barrier < stageB(s+2,0)
//  - b1 reads retire before ph1-MFMA < ph2 barrier < stageB(s+2,1)
//  - all A reads of tile s retire before ph3 barrier < stageA(s+2) (issued next tile)
// Boundary wait vmcnt(4): leaves exactly B(s+2)'s 4 loads in flight (T4).
// LDS rows [*][64] bf16, XOR swizzle chunk ^= row&7, source pre-swizzled (rule 21).
template<bool OUT_F32, bool FUSEK>
__global__ __launch_bounds__(512, 1)
void gemm256(const bf16_t* __restrict__ A, int lda, long aslab, SlabMap map, int mshift,
             const bf16_t* __restrict__ Bw, int ldb,
             const float* __restrict__ bias,
             void* __restrict__ Cout, int ldc, long cslab, int K)
{
    extern __shared__ char lds[];
    const int tid  = threadIdx.x;
    const int lane = tid & 63;
    const int w    = tid >> 6;
    const int wm   = w >> 2, wn = w & 3;   // 2M x 4N waves

    // bijective XCD swizzle (gridDim.x is always a multiple of 8 here)
    const int nwg = (int)gridDim.x;
    const int wid = (int)blockIdx.x;
    const int swz = (wid & 7) * (nwg >> 3) + (wid >> 3);
    const int bx  = swz & 7;               // N=2048 -> 8 col-blocks
    const int by  = swz >> 3;

    const int  sl    = by >> mshift;
    const long rowA0 = (long)(by & ((1 << mshift) - 1)) * 256;
    const long rowB0 = (long)bx * 256;
    const bf16_t* Ab = FUSEK ? A : (A + (long)map.a[sl] * aslab);
    const bf16_t* Wb = Bw + (long)map.w[sl] * WUNIT;
    const float*  be = bias ? (bias + (long)map.w[sl] * HH) : nullptr;

    const int srow    = tid >> 3;                       // 0..63
    const int schunk8 = ((tid & 7) ^ (srow & 7)) * 8;   // pre-swizzled src k-offset
    const int wuni    = w * 1024;                       // wave-uniform LDS base
    const int NK = K >> 6;

    auto stageA = [&](int s) {            // both A quarters of K-tile s (4 loads)
        char* dst = lds + (s & 1) * 65536;
        const int k0 = s << 6;
        const bf16_t* Aeff; int ka;
        if constexpr (FUSEK) { Aeff = A + (long)(k0 >> 11) * aslab; ka = k0 & 2047; }
        else                 { Aeff = Ab; ka = k0; }
        #pragma unroll
        for (int i = 0; i < 4; ++i)
            gload_lds16(Aeff + (rowA0 + i*64 + srow) * (long)lda + (ka + schunk8), dst + i*8192 + wuni);
    };
    auto stageB = [&](int s, int q) {     // one B quarter (2 loads)
        char* dst = lds + (s & 1) * 65536 + 32768 + q*16384;
        const int k0 = s << 6;
        #pragma unroll
        for (int j = 0; j < 2; ++j)
            gload_lds16(Wb + (rowB0 + q*128 + j*64 + srow) * (long)ldb + (k0 + schunk8), dst + j*8192 + wuni);
    };

    f32x4 acc[8][4];
    const f32x4 zero = {0.f, 0.f, 0.f, 0.f};
    #pragma unroll
    for (int i = 0; i < 8; ++i)
        #pragma unroll
        for (int j = 0; j < 4; ++j) acc[i][j] = zero;

    stageB(0,0); stageB(0,1);
    stageA(0);
    stageB(1,0); stageB(1,1);
    asm volatile("s_waitcnt vmcnt(4)" ::: "memory");
    asm volatile("s_barrier" ::: "memory");

    const int arow16 = wm*128 + (lane & 15);
    const int brow16 = wn*64  + (lane & 15);
    const int kb     = (lane >> 4) * 16;

    #define LDSA(row, kh) (*(const bf16x8*)(bufA + (row)*128 + (((kh)*64 + kb) ^ (((row) & 7) << 4))))
    #define LDSB(row, kh) (*(const bf16x8*)(bufB + (row)*128 + (((kh)*64 + kb) ^ (((row) & 7) << 4))))

    for (int s = 0; s < NK; ++s) {
        char* bufA = lds + (s & 1) * 65536;
        char* bufB = bufA + 32768;
        bf16x8 a[4][2], b0[2][2], b1[2][2];

        // ---- ph0: q0 x c0 ----
        if (s + 1 < NK) stageA(s + 1);
        #pragma unroll
        for (int cf = 0; cf < 2; ++cf) {
            const int r = brow16 + cf*16;
            #pragma unroll
            for (int kh = 0; kh < 2; ++kh) b0[cf][kh] = LDSB(r, kh);
        }
        #pragma unroll
        for (int rf = 0; rf < 4; ++rf) {
            const int r = arow16 + rf*16;
            #pragma unroll
            for (int kh = 0; kh < 2; ++kh) a[rf][kh] = LDSA(r, kh);
        }
        asm volatile("s_barrier" ::: "memory");
        __builtin_amdgcn_sched_barrier(0);
        __builtin_amdgcn_s_setprio(1);
        #pragma unroll
        for (int kh = 0; kh < 2; ++kh)
            #pragma unroll
            for (int rf = 0; rf < 4; ++rf)
                #pragma unroll
                for (int cf = 0; cf < 2; ++cf)
                    acc[rf][cf] = __builtin_amdgcn_mfma_f32_16x16x32_bf16(a[rf][kh], b0[cf][kh], acc[rf][cf], 0, 0, 0);
        __builtin_amdgcn_s_setprio(0);

        // ---- ph1: q0 x c1 ----
        #pragma unroll
        for (int cf = 0; cf < 2; ++cf) {
            const int r = brow16 + 32 + cf*16;
            #pragma unroll
            for (int kh = 0; kh < 2; ++kh) b1[cf][kh] = LDSB(r, kh);
        }
        asm volatile("s_barrier" ::: "memory");
        __builtin_amdgcn_sched_barrier(0);
        __builtin_amdgcn_s_setprio(1);
        #pragma unroll
        for (int kh = 0; kh < 2; ++kh)
            #pragma unroll
            for (int rf = 0; rf < 4; ++rf)
                #pragma unroll
                for (int cf = 0; cf < 2; ++cf)
                    acc[rf][2+cf] = __builtin_amdgcn_mfma_f32_16x16x32_bf16(a[rf][kh], b1[cf][kh], acc[rf][2+cf], 0, 0, 0);
        __builtin_amdgcn_s_setprio(0);

        // ---- ph2: q1 x c0 ----
        if (s + 2 < NK) stageB(s + 2, 0);
        #pragma unroll
        for (int rf = 0; rf < 4; ++rf) {
            const int r = arow16 + 64 + rf*16;
            #pragma unroll
            for (int kh = 0; kh < 2; ++kh) a[rf][kh] = LDSA(r, kh);
        }
        asm volatile("s_barrier" ::: "memory");
        __builtin_amdgcn_sched_barrier(0);
        __builtin_amdgcn_s_setprio(1);
        #pragma unroll
        for (int kh = 0; kh < 2; ++kh)
            #pragma unroll
            for (int rf = 0; rf < 4; ++rf)
                #pragma unroll
                for (int cf = 0; cf < 2; ++cf)
                    acc[4+rf][cf] = __builtin_amdgcn_mfma_f32_16x16x32_bf16(a[rf][kh], b0[cf][kh], acc[4+rf][cf], 0, 0, 0);
        __builtin_amdgcn_s_setprio(0);

        // ---- ph3: q1 x c1 ----
        if (s + 2 < NK) stageB(s + 2, 1);
        if (s + 1 < NK) {
            if (s + 2 < NK) asm volatile("s_waitcnt vmcnt(4)" ::: "memory");
            else            asm volatile("s_waitcnt vmcnt(0)" ::: "memory");
            asm volatile("s_barrier" ::: "memory");
            __builtin_amdgcn_sched_barrier(0);
        }
        __builtin_amdgcn_s_setprio(1);
        #pragma unroll
        for (int kh = 0; kh < 2; ++kh)
            #pragma unroll
            for (int rf = 0; rf < 4; ++rf)
                #pragma unroll
                for (int cf = 0; cf < 2; ++cf)
                    acc[4+rf][2+cf] = __builtin_amdgcn_mfma_f32_16x16x32_bf16(a[rf][kh], b1[cf][kh], acc[4+rf][2+cf], 0, 0, 0);
        __builtin_amdgcn_s_setprio(0);
    }
    #undef LDSA
    #undef LDSB

    // C/D layout: col = lane&15, row = (lane>>4)*4 + reg  [m89/m91]
    const long crow0 = rowA0 + wm*128 + ((lane >> 4) * 4);
    const int  ccol0 = (int)rowB0 + wn*64 + (lane & 15);
    const long cbase = (long)sl * cslab;
    #pragma unroll
    for (int rf = 0; rf < 8; ++rf) {
        #pragma unroll
        for (int cf = 0; cf < 4; ++cf) {
            const int col = ccol0 + cf*16;
            const float bv = be ? be[col] : 0.f;
            #pragma unroll
            for (int r = 0; r < 4; ++r) {
                const long row = crow0 + rf*16 + r;
                const float val = acc[rf][cf][r] + bv;
                if constexpr (OUT_F32) ((float*)Cout)[cbase + row*(long)ldc + col] = val;
                else ((bf16_t*)Cout)[cbase + row*(long)ldc + col] = __float2bfloat16(val);
            }
        }
    }
}

__global__ __launch_bounds__(256)
void f2b_kernel(const float* __restrict__ in, bf16_t* __restrict__ out, long n)
{
    long i = ((long)blockIdx.x * 256 + threadIdx.x) * 4;
    const long stride = (long)gridDim.x * 256 * 4;
    for (; i < n; i += stride) {
        const float4 v = *(const float4*)(in + i);
        __hip_bfloat162 lo, hi;
        lo.x = __float2bfloat16(v.x); lo.y = __float2bfloat16(v.y);
        hi.x = __float2bfloat16(v.z); hi.y = __float2bfloat16(v.w);
        *(__hip_bfloat162*)(out + i)     = lo;
        *(__hip_bfloat162*)(out + i + 2) = hi;
    }
}

// batched f2b over 4 equal-size [3,2048,2048] tensors
__global__ __launch_bounds__(256)
void f2b4_kernel(Ptrs4 p)
{
    const long total = 4 * WT;
    long i = ((long)blockIdx.x * 256 + threadIdx.x) * 4;
    const long stride = (long)gridDim.x * 256 * 4;
    for (; i < total; i += stride) {
        const int  t   = (int)(i / WT);
        const long off = i - (long)t * WT;
        const float4 v = *(const float4*)(p.in[t] + off);
        __hip_bfloat162 lo, hi;
        lo.x = __float2bfloat16(v.x); lo.y = __float2bfloat16(v.y);
        hi.x = __float2bfloat16(v.z); hi.y = __float2bfloat16(v.w);
        *(__hip_bfloat162*)(p.out[t] + off)     = lo;
        *(__hip_bfloat162*)(p.out[t] + off + 2) = hi;
    }
}

// batched transpose-convert: out[mat][c][r] = (bf16) in[mat][r][c], 4 tensors x 3 mats
__global__ __launch_bounds__(256)
void f2bT4_kernel(Ptrs4 p)
{
    __shared__ float sm[64][65];
    const int gmat = blockIdx.x >> 10;       // 0..11
    const int t    = gmat / 3, m = gmat % 3;
    const int tile = blockIdx.x & 1023;
    const int tr   = tile >> 5, tc = tile & 31;
    const int lr = threadIdx.x >> 4;
    const int lc = (threadIdx.x & 15) * 4;
    const float* src = p.in[t] + (long)m*WUNIT + ((long)tr*64)*2048 + tc*64;
    #pragma unroll
    for (int it = 0; it < 4; ++it) {
        const int r = lr + it*16;
        const float4 v = *(const float4*)(src + (long)r*2048 + lc);
        sm[r][lc] = v.x; sm[r][lc+1] = v.y; sm[r][lc+2] = v.z; sm[r][lc+3] = v.w;
    }
    __syncthreads();
    bf16_t* dst = p.out[t] + (long)m*WUNIT + ((long)tc*64)*2048 + tr*64;
    #pragma unroll
    for (int it = 0; it < 4; ++it) {
        const int r = lr + it*16;
        __hip_bfloat162 p0, p1;
        p0.x = __float2bfloat16(sm[lc+0][r]); p0.y = __float2bfloat16(sm[lc+1][r]);
        p1.x = __float2bfloat16(sm[lc+2][r]); p1.y = __float2bfloat16(sm[lc+3][r]);
        *(__hip_bfloat162*)(dst + (long)r*2048 + lc)     = p0;
        *(__hip_bfloat162*)(dst + (long)r*2048 + lc + 2) = p1;
    }
}

// all 16 bias folds in one dispatch: out[g2] = sum_k W2[g2*ld+k]*b1[k] + badd[g2]
__global__ __launch_bounds__(256)
void biasfold_all(FoldPack p)
{
    const FoldJob jb = p.j[blockIdx.x >> 11];
    const int g2 = blockIdx.x & 2047;
    const int t  = threadIdx.x;
    float s = 0.f;
    for (int k = t; k < jb.ld; k += 256) s += jb.W2[(long)g2*jb.ld + k] * jb.b1[k];
    #pragma unroll
    for (int off = 32; off > 0; off >>= 1) s += __shfl_xor(s, off);
    __shared__ float rs[4];
    if ((t & 63) == 0) rs[t >> 6] = s;
    __syncthreads();
    if (t == 0) jb.out[g2] = rs[0] + rs[1] + rs[2] + rs[3] + jb.badd[g2];
}

// one wave per (v, b, head): q_len=1 attention over the 2 other views.
__global__ __launch_bounds__(256)
void attn_kernel(const bf16_t* __restrict__ q2, const bf16_t* __restrict__ k2,
                 const bf16_t* __restrict__ v2, bf16_t* __restrict__ ctx, int bshift)
{
    const long gw = (long)blockIdx.x * 4 + (threadIdx.x >> 6);
    const int lane = threadIdx.x & 63;
    const int  v_  = (int)(gw >> (bshift + 4));
    const long rem = gw & ((1L << (bshift + 4)) - 1);
    const long b   = rem >> 4;
    const int  n   = (int)(rem & 15);
    const long base = ((((long)v_ << bshift) + b)) * HH + (long)n * 128 + lane * 2;

    const __hip_bfloat162 qv = *(const __hip_bfloat162*)(q2 + base);
    const float q0 = __bfloat162float(qv.x), q1 = __bfloat162float(qv.y);
    float s[2], va[2], vb[2];
    #pragma unroll
    for (int j = 0; j < 2; ++j) {
        const long kb = ((((long)(v_*2 + j) << bshift) + b)) * HH + (long)n * 128 + lane * 2;
        const __hip_bfloat162 kv = *(const __hip_bfloat162*)(k2 + kb);
        float p = q0 * __bfloat162float(kv.x) + q1 * __bfloat162float(kv.y);
        #pragma unroll
        for (int off = 32; off > 0; off >>= 1) p += __shfl_xor(p, off);
        s[j] = p;
        const __hip_bfloat162 vv = *(const __hip_bfloat162*)(v2 + kb);
        va[j] = __bfloat162float(vv.x); vb[j] = __bfloat162float(vv.y);
    }
    const float scale = 0.08838834764831845f; // 1/sqrt(128)
    const float s0 = s[0] * scale, s1 = s[1] * scale;
    const float m  = fmaxf(s0, s1);
    const float e0 = expf(s0 - m), e1 = expf(s1 - m);
    const float inv = 1.0f / (e0 + e1);
    const float a0 = e0 * inv, a1 = e1 * inv;
    __hip_bfloat162 o;
    o.x = __float2bfloat16(a0 * va[0] + a1 * va[1]);
    o.y = __float2bfloat16(a0 * vb[0] + a1 * vb[1]);
    *(__hip_bfloat162*)(ctx + base) = o;
}

// residual (views[0] chunk) + LayerNorm, one block per row
__global__ __launch_bounds__(256)
void ln_kernel(const float* __restrict__ proj, const float* __restrict__ v0,
               const float* __restrict__ gamma, const float* __restrict__ beta,
               float* __restrict__ out)
{
    const long b = blockIdx.x;
    const int t = threadIdx.x;
    const float* pr = proj + b * HH;
    const float* vw = v0 + b * HH;
    float x[8]; float s = 0.f, s2 = 0.f;
    #pragma unroll
    for (int k = 0; k < 8; ++k) {
        const int idx = t + k * 256;
        x[k] = vw[idx] + pr[idx];
        s += x[k]; s2 += x[k] * x[k];
    }
    #pragma unroll
    for (int off = 32; off > 0; off >>= 1) { s += __shfl_xor(s, off); s2 += __shfl_xor(s2, off); }
    __shared__ float rs[4], rs2[4];
    if ((t & 63) == 0) { rs[t >> 6] = s; rs2[t >> 6] = s2; }
    __syncthreads();
    s  = rs[0] + rs[1] + rs[2] + rs[3];
    s2 = rs2[0] + rs2[1] + rs2[2] + rs2[3];
    const float mu  = s * (1.0f / 2048.0f);
    const float var = s2 * (1.0f / 2048.0f) - mu * mu;
    const float rstd = rsqrtf(var + 1e-5f);
    #pragma unroll
    for (int k = 0; k < 8; ++k) {
        const int idx = t + k * 256;
        out[b * HH + idx] = (x[k] - mu) * rstd * gamma[idx] + beta[idx];
    }
}

extern "C" void kernel_launch(void* const* d_in, const int* in_sizes, int n_in,
                              void* d_out, int out_size, void* d_ws, size_t ws_size,
                              hipStream_t stream)
{
    const float* views = (const float*)d_in[0];
    const float* Wq   = (const float*)d_in[1];  const float* bq   = (const float*)d_in[2];
    const float* Wk   = (const float*)d_in[3];  const float* bk   = (const float*)d_in[4];
    const float* Wv   = (const float*)d_in[5];  const float* bv   = (const float*)d_in[6];
    const float* Wiq  = (const float*)d_in[7];  const float* biq  = (const float*)d_in[8];
    const float* Wik  = (const float*)d_in[9];  const float* bik  = (const float*)d_in[10];
    const float* Wiv  = (const float*)d_in[11]; const float* biv  = (const float*)d_in[12];
    const float* Wo   = (const float*)d_in[13]; const float* bo   = (const float*)d_in[14];
    const float* Wout = (const float*)d_in[15]; const float* bout = (const float*)d_in[16];
    const float* gamma= (const float*)d_in[17]; const float* beta = (const float*)d_in[18];

    static bool attr_set = false;
    if (!attr_set) {
        hipFuncSetAttribute((const void*)gemm256<false,false>,
                            hipFuncAttributeMaxDynamicSharedMemorySize, LDS_TOTAL);
        hipFuncSetAttribute((const void*)gemm256<true,true>,
                            hipFuncAttributeMaxDynamicSharedMemorySize, LDS_TOTAL);
        attr_set = true;
    }

    // ---- workspace: persistent folded weights + overlaid {fold-scratch | activations} ----
    char* ws = (char*)d_ws;
    bf16_t* WQ2  = (bf16_t*)ws;                  // 3u folded q
    bf16_t* WK2  = WQ2 + 3*WUNIT;                // 6u folded k (per pair)
    bf16_t* WV2  = WK2 + 6*WUNIT;                // 6u folded v
    bf16_t* WFIN = WV2 + 6*WUNIT;                // 3u folded final, [2048][6144]
    float*  BQ2  = (float*)(WFIN + 3*WUNIT);
    float*  BK2  = BQ2 + 3*HH;
    float*  BV2  = BK2 + 6*HH;
    float*  BFIN = BV2 + 6*HH;
    const long FIXED = 18L*WUNIT*2 + 16L*HH*4;   // 151,126,016 B

    char* R = ws + FIXED;
    // fold-phase transient (dead before activations are written):
    bf16_t* WIQ   = (bf16_t*)R;
    bf16_t* WIK   = WIQ  + 3*WUNIT;
    bf16_t* WIV   = WIK  + 3*WUNIT;
    bf16_t* WOUTB = WIV  + 3*WUNIT;
    bf16_t* WQT   = WOUTB+ 3*WUNIT;
    bf16_t* WKT   = WQT  + 3*WUNIT;
    bf16_t* WVT   = WKT  + 3*WUNIT;
    bf16_t* WOT   = WVT  + 3*WUNIT;              // scratch total 24u = 201.3 MB

    // ---- adaptive batch chunking ----
    const long scratch = 24L*WUNIT*2;
    long Bc = 8192;
    while (Bc > 256) {
        long need = Bc * 73728L; if (need < scratch) need = scratch;
        if (FIXED + need <= (long)ws_size) break;
        Bc >>= 1;
    }
    const int mshift = __builtin_ctzl((unsigned long)Bc) - 8;  // log2(Bc/256)
    const int bshift = __builtin_ctzl((unsigned long)Bc);      // log2(Bc)
    const long S1 = Bc * HH;

    bf16_t* VBF = (bf16_t*)R;            // views bf16 -> later ctx (3 slabs)
    bf16_t* Q2B = VBF + 3*S1;            // q2 (3)
    bf16_t* K2  = Q2B + 3*S1;            // k2 (6)
    bf16_t* V2  = K2  + 6*S1;            // v2 (6)
    float*  PROJ= (float*)K2;            // aliases K2 (dead after attn)

    const SlabMap mp3  = {{0,1,2,0,0,0},{0,1,2,0,0,0}};
    const SlabMap mp6k = {{1,2,0,2,0,1},{0,1,2,3,4,5}};  // a = oth[v][j], w = pair idx
    const SlabMap mpfk = {{0,0,1,1,2,2},{1,2,0,2,0,1}};  // fold: A=Wi*[v], W=W*T[oth]
    const SlabMap mp1  = {{0,0,0,0,0,0},{0,0,0,0,0,0}};
    const int oth[3][2] = {{1,2},{0,2},{0,1}};

    // ---- one-time: weight conversions (2 batched dispatches) ----
    {
        Ptrs4 c1 = {{Wiq, Wik, Wiv, Wout}, {WIQ, WIK, WIV, WOUTB}};
        f2b4_kernel<<<8192, 256, 0, stream>>>(c1);
        Ptrs4 c2 = {{Wq, Wk, Wv, Wo}, {WQT, WKT, WVT, WOT}};
        f2bT4_kernel<<<12288, 256, 0, stream>>>(c2);
    }
    // ---- one-time: weight folds ----
    gemm256<false,false><<<192, 512, LDS_TOTAL, stream>>>(WIQ, 2048, WUNIT, mp3,  3, WQT, 2048, nullptr, (void*)WQ2, 2048, WUNIT, 2048);
    gemm256<false,false><<<384, 512, LDS_TOTAL, stream>>>(WIK, 2048, WUNIT, mpfk, 3, WKT, 2048, nullptr, (void*)WK2, 2048, WUNIT, 2048);
    gemm256<false,false><<<384, 512, LDS_TOTAL, stream>>>(WIV, 2048, WUNIT, mpfk, 3, WVT, 2048, nullptr, (void*)WV2, 2048, WUNIT, 2048);
    gemm256<false,false><<<192, 512, LDS_TOTAL, stream>>>(WOUTB, 6144, 2048, mp3, 3, WOT, 2048, nullptr, (void*)WFIN, 6144, 2048, 2048);

    // ---- one-time: all 16 exact bias folds in one dispatch ----
    {
        FoldPack fp;
        for (int v = 0; v < 3; ++v)
            fp.j[v] = { Wiq + (long)v*WUNIT, bq + v*HH, biq + v*HH, BQ2 + v*HH, 2048 };
        for (int v = 0; v < 3; ++v)
            for (int j = 0; j < 2; ++j) {
                const int p = v*2 + j, o = oth[v][j];
                fp.j[3 + p] = { Wik + (long)v*WUNIT, bk + o*HH, bik + v*HH, BK2 + p*HH, 2048 };
                fp.j[9 + p] = { Wiv + (long)v*WUNIT, bv + o*HH, biv + v*HH, BV2 + p*HH, 2048 };
            }
        fp.j[15] = { Wout, bo, bout, BFIN, 6144 };
        biasfold_all<<<32768, 256, 0, stream>>>(fp);
    }

    const int nwg3 = 8 * 3 * (int)(Bc >> 8);
    const int nwg6 = 8 * 6 * (int)(Bc >> 8);
    const int nwg1 = 8 * 1 * (int)(Bc >> 8);
    const int vgrid = (int)((S1 / 1024 > 8192) ? 8192 : S1 / 1024);

    for (long b0 = 0; b0 < BB; b0 += Bc) {
        if (Bc == 8192) {
            f2b_kernel<<<8192, 256, 0, stream>>>(views, VBF, 3*BH);
        } else {
            for (int v = 0; v < 3; ++v)
                f2b_kernel<<<vgrid, 256, 0, stream>>>(views + v*BH + b0*HH, VBF + v*S1, S1);
        }
        // q2 / k2 / v2 directly from views via folded weights
        gemm256<false,false><<<nwg3, 512, LDS_TOTAL, stream>>>(VBF, 2048, S1, mp3,  mshift, WQ2, 2048, BQ2, (void*)Q2B, 2048, S1, 2048);
        gemm256<false,false><<<nwg6, 512, LDS_TOTAL, stream>>>(VBF, 2048, S1, mp6k, mshift, WK2, 2048, BK2, (void*)K2,  2048, S1, 2048);
        gemm256<false,false><<<nwg6, 512, LDS_TOTAL, stream>>>(VBF, 2048, S1, mp6k, mshift, WV2, 2048, BV2, (void*)V2,  2048, S1, 2048);
        // attention: ctx -> VBF (views_bf dead)
        attn_kernel<<<(int)(12*Bc), 256, 0, stream>>>(Q2B, K2, V2, VBF, bshift);
        // fused projection: proj = sum_v ctx[v] @ WFIN_v^T + BFIN (K=6144 over ctx slabs)
        gemm256<true,true><<<nwg1, 512, LDS_TOTAL, stream>>>(VBF, 2048, S1, mp1, mshift, WFIN, 6144, BFIN, (void*)PROJ, 2048, 0, 6144);
        // residual + LayerNorm
        ln_kernel<<<(int)Bc, 256, 0, stream>>>(PROJ, views + b0*HH, gamma, beta, ((float*)d_out) + b0*HH);
    }
}

// Round 7
// 1646.803 us; speedup vs baseline: 1.5029x; 1.0316x over previous
//
#include <hip/hip_runtime.h>
#include <hip/hip_bf16.h>

typedef __attribute__((ext_vector_type(8))) __bf16 bf16x8;
typedef __attribute__((ext_vector_type(4))) float f32x4;
typedef __hip_bfloat16 bf16_t;

#define BB 8192L
#define HH 2048L
#define BH (8192L*2048L)      // elements per full [B,H] slab
#define WUNIT (2048L*2048L)   // elements per HxH weight unit
#define WT (3L*2048L*2048L)   // elements per [3,H,H] weight tensor
#define LDS_TOTAL 163840      // A: 3 x 32KB triple-buffer, B: 2 x 32KB double-buffer

struct SlabMap { int a[6]; int w[6]; };
struct Ptrs4 { const float* in[4]; bf16_t* out[4]; };
struct FoldJob { const float* W2; const float* b1; const float* badd; float* out; int ld; };
struct FoldPack { FoldJob j[16]; };
struct GJob { const bf16_t* A; const bf16_t* Bw; bf16_t* C; int lda; int ldc; };
struct GJobs { GJob j[18]; };

__device__ __forceinline__ void gload_lds16(const void* g, void* l) {
    __builtin_amdgcn_global_load_lds((__attribute__((address_space(1))) void*)g,
                                     (__attribute__((address_space(3))) void*)l, 16, 0, 0);
}

// 8-phase 256x256 GEMM core: C[M,N] = A[M,K] @ W[N,K]^T (+bias), BK=64,
// 512 thr = 8 waves (2M x 4N), wave tile 128x64.
// A triple-buffered (slot s%3), B double-buffered (slot s&1) in 160KB LDS.
// Per K-tile s, 4 phases x 16 MFMA: ph0 stages A(s+2), ph2/ph3 stage B(s+2)
// quarters; phase order {stage; ds_read; s_barrier; sched_barrier; MFMA}.
// Boundary: vmcnt(8) leaves the full K-tile (s+2)'s 8 loads in flight (T4
// depth 2, never drain mid-loop); tail s+2>=NK uses vmcnt(0) (vacuous-pass fix).
// Race audit: A-slot (s+2)%3 last read tile s-1, retired at s-1->s boundary
// barrier; B(s+2,q) overwrites region whose LDS reads were consumed (lgkmcnt
// before MFMA) before the barrier preceding the stage issue.
// LDS rows [*][64] bf16, XOR swizzle chunk ^= row&7, source pre-swizzled (rule 21).
template<bool OUT_F32, bool FUSEK>
__device__ __forceinline__ void gemm_core(
    const bf16_t* __restrict__ A, int lda, long aslab,
    const bf16_t* __restrict__ Wb, int ldb,
    const float* __restrict__ be,
    void* __restrict__ Cout, int ldc,
    long rowA0, long rowB0, int K, char* lds)
{
    const int tid  = threadIdx.x;
    const int lane = tid & 63;
    const int w    = tid >> 6;
    const int wm   = w >> 2, wn = w & 3;   // 2M x 4N waves

    const int srow    = tid >> 3;                       // 0..63
    const int schunk8 = ((tid & 7) ^ (srow & 7)) * 8;   // pre-swizzled src k-offset
    const int wuni    = w * 1024;                       // wave-uniform LDS base
    const int NK = K >> 6;

    auto stageA = [&](int s) {            // all 4 A quarters of K-tile s
        char* dst = lds + (s % 3) * 32768;
        const int k0 = s << 6;
        const bf16_t* Aeff; int ka;
        if constexpr (FUSEK) { Aeff = A + (long)(k0 >> 11) * aslab; ka = k0 & 2047; }
        else                 { Aeff = A; ka = k0; }
        #pragma unroll
        for (int i = 0; i < 4; ++i)
            gload_lds16(Aeff + (rowA0 + i*64 + srow) * (long)lda + (ka + schunk8), dst + i*8192 + wuni);
    };
    auto stageB = [&](int s, int q) {     // one B quarter (2 loads)
        char* dst = lds + 98304 + (s & 1) * 32768 + q*16384;
        const int k0 = s << 6;
        #pragma unroll
        for (int j = 0; j < 2; ++j)
            gload_lds16(Wb + (rowB0 + q*128 + j*64 + srow) * (long)ldb + (k0 + schunk8), dst + j*8192 + wuni);
    };

    f32x4 acc[8][4];
    const f32x4 zero = {0.f, 0.f, 0.f, 0.f};
    #pragma unroll
    for (int i = 0; i < 8; ++i)
        #pragma unroll
        for (int j = 0; j < 4; ++j) acc[i][j] = zero;

    // prologue: tiles 0 and 1 staged; wait tile 0 landed, tile 1's 8 in flight
    stageA(0); stageB(0,0); stageB(0,1);
    stageA(1); stageB(1,0); stageB(1,1);
    asm volatile("s_waitcnt vmcnt(8)" ::: "memory");
    asm volatile("s_barrier" ::: "memory");

    const int arow16 = wm*128 + (lane & 15);
    const int brow16 = wn*64  + (lane & 15);
    const int kb     = (lane >> 4) * 16;

    #define LDSA(row, kh) (*(const bf16x8*)(bufA + (row)*128 + (((kh)*64 + kb) ^ (((row) & 7) << 4))))
    #define LDSB(row, kh) (*(const bf16x8*)(bufB + (row)*128 + (((kh)*64 + kb) ^ (((row) & 7) << 4))))

    for (int s = 0; s < NK; ++s) {
        char* bufA = lds + (s % 3) * 32768;
        char* bufB = lds + 98304 + (s & 1) * 32768;
        bf16x8 a[4][2], b0[2][2], b1[2][2];

        // ---- ph0: q0 x c0 ----
        if (s + 2 < NK) stageA(s + 2);
        #pragma unroll
        for (int cf = 0; cf < 2; ++cf) {
            const int r = brow16 + cf*16;
            #pragma unroll
            for (int kh = 0; kh < 2; ++kh) b0[cf][kh] = LDSB(r, kh);
        }
        #pragma unroll
        for (int rf = 0; rf < 4; ++rf) {
            const int r = arow16 + rf*16;
            #pragma unroll
            for (int kh = 0; kh < 2; ++kh) a[rf][kh] = LDSA(r, kh);
        }
        asm volatile("s_barrier" ::: "memory");
        __builtin_amdgcn_sched_barrier(0);
        __builtin_amdgcn_s_setprio(1);
        #pragma unroll
        for (int kh = 0; kh < 2; ++kh)
            #pragma unroll
            for (int rf = 0; rf < 4; ++rf)
                #pragma unroll
                for (int cf = 0; cf < 2; ++cf)
                    acc[rf][cf] = __builtin_amdgcn_mfma_f32_16x16x32_bf16(a[rf][kh], b0[cf][kh], acc[rf][cf], 0, 0, 0);
        __builtin_amdgcn_s_setprio(0);

        // ---- ph1: q0 x c1 ----
        #pragma unroll
        for (int cf = 0; cf < 2; ++cf) {
            const int r = brow16 + 32 + cf*16;
            #pragma unroll
            for (int kh = 0; kh < 2; ++kh) b1[cf][kh] = LDSB(r, kh);
        }
        asm volatile("s_barrier" ::: "memory");
        __builtin_amdgcn_sched_barrier(0);
        __builtin_amdgcn_s_setprio(1);
        #pragma unroll
        for (int kh = 0; kh < 2; ++kh)
            #pragma unroll
            for (int rf = 0; rf < 4; ++rf)
                #pragma unroll
                for (int cf = 0; cf < 2; ++cf)
                    acc[rf][2+cf] = __builtin_amdgcn_mfma_f32_16x16x32_bf16(a[rf][kh], b1[cf][kh], acc[rf][2+cf], 0, 0, 0);
        __builtin_amdgcn_s_setprio(0);

        // ---- ph2: q1 x c0 ----
        if (s + 2 < NK) stageB(s + 2, 0);
        #pragma unroll
        for (int rf = 0; rf < 4; ++rf) {
            const int r = arow16 + 64 + rf*16;
            #pragma unroll
            for (int kh = 0; kh < 2; ++kh) a[rf][kh] = LDSA(r, kh);
        }
        asm volatile("s_barrier" ::: "memory");
        __builtin_amdgcn_sched_barrier(0);
        __builtin_amdgcn_s_setprio(1);
        #pragma unroll
        for (int kh = 0; kh < 2; ++kh)
            #pragma unroll
            for (int rf = 0; rf < 4; ++rf)
                #pragma unroll
                for (int cf = 0; cf < 2; ++cf)
                    acc[4+rf][cf] = __builtin_amdgcn_mfma_f32_16x16x32_bf16(a[rf][kh], b0[cf][kh], acc[4+rf][cf], 0, 0, 0);
        __builtin_amdgcn_s_setprio(0);

        // ---- ph3: q1 x c1 ----
        if (s + 2 < NK) stageB(s + 2, 1);
        if (s + 1 < NK) {
            if (s + 2 < NK) asm volatile("s_waitcnt vmcnt(8)" ::: "memory");
            else            asm volatile("s_waitcnt vmcnt(0)" ::: "memory");
            asm volatile("s_barrier" ::: "memory");
            __builtin_amdgcn_sched_barrier(0);
        }
        __builtin_amdgcn_s_setprio(1);
        #pragma unroll
        for (int kh = 0; kh < 2; ++kh)
            #pragma unroll
            for (int rf = 0; rf < 4; ++rf)
                #pragma unroll
                for (int cf = 0; cf < 2; ++cf)
                    acc[4+rf][2+cf] = __builtin_amdgcn_mfma_f32_16x16x32_bf16(a[rf][kh], b1[cf][kh], acc[4+rf][2+cf], 0, 0, 0);
        __builtin_amdgcn_s_setprio(0);
    }
    #undef LDSA
    #undef LDSB

    // C/D layout: col = lane&15, row = (lane>>4)*4 + reg  [m89/m91]
    const long crow0 = rowA0 + wm*128 + ((lane >> 4) * 4);
    const int  ccol0 = (int)rowB0 + wn*64 + (lane & 15);
    #pragma unroll
    for (int rf = 0; rf < 8; ++rf) {
        #pragma unroll
        for (int cf = 0; cf < 4; ++cf) {
            const int col = ccol0 + cf*16;
            const float bv = be ? be[col] : 0.f;
            #pragma unroll
            for (int r = 0; r < 4; ++r) {
                const long row = crow0 + rf*16 + r;
                const float val = acc[rf][cf][r] + bv;
                if constexpr (OUT_F32) ((float*)Cout)[row*(long)ldc + col] = val;
                else ((bf16_t*)Cout)[row*(long)ldc + col] = __float2bfloat16(val);
            }
        }
    }
}

template<bool OUT_F32, bool FUSEK>
__global__ __launch_bounds__(512, 1)
void gemm256(const bf16_t* __restrict__ A, int lda, long aslab, SlabMap map, int mshift,
             const bf16_t* __restrict__ Bw, int ldb,
             const float* __restrict__ bias,
             void* __restrict__ Cout, int ldc, long cslab, int K)
{
    extern __shared__ char lds[];
    // bijective XCD swizzle (gridDim.x is always a multiple of 8 here)
    const int nwg = (int)gridDim.x;
    const int wid = (int)blockIdx.x;
    const int swz = (wid & 7) * (nwg >> 3) + (wid >> 3);
    const int bx  = swz & 7;               // N=2048 -> 8 col-blocks
    const int by  = swz >> 3;

    const int  sl    = by >> mshift;
    const long rowA0 = (long)(by & ((1 << mshift) - 1)) * 256;
    const long rowB0 = (long)bx * 256;
    const bf16_t* Ab = FUSEK ? A : (A + (long)map.a[sl] * aslab);
    const bf16_t* Wb = Bw + (long)map.w[sl] * WUNIT;
    const float*  be = bias ? (bias + (long)map.w[sl] * HH) : nullptr;
    const long cbase = (long)sl * cslab;
    void* Cj = OUT_F32 ? (void*)((float*)Cout + cbase) : (void*)((bf16_t*)Cout + cbase);
    gemm_core<OUT_F32, FUSEK>(Ab, lda, aslab, Wb, ldb, be, Cj, ldc, rowA0, rowB0, K, lds);
}

// all 18 weight-fold GEMMs (M=N=K=2048 each) in one dispatch: 18 jobs x 64 blocks
__global__ __launch_bounds__(512, 1)
void gemm_fold(GJobs js)
{
    extern __shared__ char lds[];
    const int nwg = (int)gridDim.x;     // 1152, multiple of 8
    const int wid = (int)blockIdx.x;
    const int swz = (wid & 7) * (nwg >> 3) + (wid >> 3);
    const GJob jb = js.j[swz >> 6];
    const int inner = swz & 63;
    const long rowA0 = (long)(inner >> 3) * 256;
    const long rowB0 = (long)(inner & 7) * 256;
    gemm_core<false, false>(jb.A, jb.lda, 0L, jb.Bw, 2048, nullptr,
                            (void*)jb.C, jb.ldc, rowA0, rowB0, 2048, lds);
}

__global__ __launch_bounds__(256)
void f2b_kernel(const float* __restrict__ in, bf16_t* __restrict__ out, long n)
{
    long i = ((long)blockIdx.x * 256 + threadIdx.x) * 4;
    const long stride = (long)gridDim.x * 256 * 4;
    for (; i < n; i += stride) {
        const float4 v = *(const float4*)(in + i);
        __hip_bfloat162 lo, hi;
        lo.x = __float2bfloat16(v.x); lo.y = __float2bfloat16(v.y);
        hi.x = __float2bfloat16(v.z); hi.y = __float2bfloat16(v.w);
        *(__hip_bfloat162*)(out + i)     = lo;
        *(__hip_bfloat162*)(out + i + 2) = hi;
    }
}

// batched f2b over 4 equal-size [3,2048,2048] tensors
__global__ __launch_bounds__(256)
void f2b4_kernel(Ptrs4 p)
{
    const long total = 4 * WT;
    long i = ((long)blockIdx.x * 256 + threadIdx.x) * 4;
    const long stride = (long)gridDim.x * 256 * 4;
    for (; i < total; i += stride) {
        const int  t   = (int)(i / WT);
        const long off = i - (long)t * WT;
        const float4 v = *(const float4*)(p.in[t] + off);
        __hip_bfloat162 lo, hi;
        lo.x = __float2bfloat16(v.x); lo.y = __float2bfloat16(v.y);
        hi.x = __float2bfloat16(v.z); hi.y = __float2bfloat16(v.w);
        *(__hip_bfloat162*)(p.out[t] + off)     = lo;
        *(__hip_bfloat162*)(p.out[t] + off + 2) = hi;
    }
}

// batched transpose-convert: out[mat][c][r] = (bf16) in[mat][r][c], 4 tensors x 3 mats
__global__ __launch_bounds__(256)
void f2bT4_kernel(Ptrs4 p)
{
    __shared__ float sm[64][65];
    const int gmat = blockIdx.x >> 10;       // 0..11
    const int t    = gmat / 3, m = gmat % 3;
    const int tile = blockIdx.x & 1023;
    const int tr   = tile >> 5, tc = tile & 31;
    const int lr = threadIdx.x >> 4;
    const int lc = (threadIdx.x & 15) * 4;
    const float* src = p.in[t] + (long)m*WUNIT + ((long)tr*64)*2048 + tc*64;
    #pragma unroll
    for (int it = 0; it < 4; ++it) {
        const int r = lr + it*16;
        const float4 v = *(const float4*)(src + (long)r*2048 + lc);
        sm[r][lc] = v.x; sm[r][lc+1] = v.y; sm[r][lc+2] = v.z; sm[r][lc+3] = v.w;
    }
    __syncthreads();
    bf16_t* dst = p.out[t] + (long)m*WUNIT + ((long)tc*64)*2048 + tr*64;
    #pragma unroll
    for (int it = 0; it < 4; ++it) {
        const int r = lr + it*16;
        __hip_bfloat162 p0, p1;
        p0.x = __float2bfloat16(sm[lc+0][r]); p0.y = __float2bfloat16(sm[lc+1][r]);
        p1.x = __float2bfloat16(sm[lc+2][r]); p1.y = __float2bfloat16(sm[lc+3][r]);
        *(__hip_bfloat162*)(dst + (long)r*2048 + lc)     = p0;
        *(__hip_bfloat162*)(dst + (long)r*2048 + lc + 2) = p1;
    }
}

// all 16 bias folds in one dispatch: out[g2] = sum_k W2[g2*ld+k]*b1[k] + badd[g2]
__global__ __launch_bounds__(256)
void biasfold_all(FoldPack p)
{
    const FoldJob jb = p.j[blockIdx.x >> 11];
    const int g2 = blockIdx.x & 2047;
    const int t  = threadIdx.x;
    float s = 0.f;
    for (int k = t; k < jb.ld; k += 256) s += jb.W2[(long)g2*jb.ld + k] * jb.b1[k];
    #pragma unroll
    for (int off = 32; off > 0; off >>= 1) s += __shfl_xor(s, off);
    __shared__ float rs[4];
    if ((t & 63) == 0) rs[t >> 6] = s;
    __syncthreads();
    if (t == 0) jb.out[g2] = rs[0] + rs[1] + rs[2] + rs[3] + jb.badd[g2];
}

// one wave per (v, b, head): q_len=1 attention over the 2 other views.
__global__ __launch_bounds__(256)
void attn_kernel(const bf16_t* __restrict__ q2, const bf16_t* __restrict__ k2,
                 const bf16_t* __restrict__ v2, bf16_t* __restrict__ ctx, int bshift)
{
    const long gw = (long)blockIdx.x * 4 + (threadIdx.x >> 6);
    const int lane = threadIdx.x & 63;
    const int  v_  = (int)(gw >> (bshift + 4));
    const long rem = gw & ((1L << (bshift + 4)) - 1);
    const long b   = rem >> 4;
    const int  n   = (int)(rem & 15);
    const long base = ((((long)v_ << bshift) + b)) * HH + (long)n * 128 + lane * 2;

    const __hip_bfloat162 qv = *(const __hip_bfloat162*)(q2 + base);
    const float q0 = __bfloat162float(qv.x), q1 = __bfloat162float(qv.y);
    float s[2], va[2], vb[2];
    #pragma unroll
    for (int j = 0; j < 2; ++j) {
        const long kb = ((((long)(v_*2 + j) << bshift) + b)) * HH + (long)n * 128 + lane * 2;
        const __hip_bfloat162 kv = *(const __hip_bfloat162*)(k2 + kb);
        float p = q0 * __bfloat162float(kv.x) + q1 * __bfloat162float(kv.y);
        #pragma unroll
        for (int off = 32; off > 0; off >>= 1) p += __shfl_xor(p, off);
        s[j] = p;
        const __hip_bfloat162 vv = *(const __hip_bfloat162*)(v2 + kb);
        va[j] = __bfloat162float(vv.x); vb[j] = __bfloat162float(vv.y);
    }
    const float scale = 0.08838834764831845f; // 1/sqrt(128)
    const float s0 = s[0] * scale, s1 = s[1] * scale;
    const float m  = fmaxf(s0, s1);
    const float e0 = expf(s0 - m), e1 = expf(s1 - m);
    const float inv = 1.0f / (e0 + e1);
    const float a0 = e0 * inv, a1 = e1 * inv;
    __hip_bfloat162 o;
    o.x = __float2bfloat16(a0 * va[0] + a1 * va[1]);
    o.y = __float2bfloat16(a0 * vb[0] + a1 * vb[1]);
    *(__hip_bfloat162*)(ctx + base) = o;
}

// residual (views[0] chunk) + LayerNorm, one block per row
__global__ __launch_bounds__(256)
void ln_kernel(const float* __restrict__ proj, const float* __restrict__ v0,
               const float* __restrict__ gamma, const float* __restrict__ beta,
               float* __restrict__ out)
{
    const long b = blockIdx.x;
    const int t = threadIdx.x;
    const float* pr = proj + b * HH;
    const float* vw = v0 + b * HH;
    float x[8]; float s = 0.f, s2 = 0.f;
    #pragma unroll
    for (int k = 0; k < 8; ++k) {
        const int idx = t + k * 256;
        x[k] = vw[idx] + pr[idx];
        s += x[k]; s2 += x[k] * x[k];
    }
    #pragma unroll
    for (int off = 32; off > 0; off >>= 1) { s += __shfl_xor(s, off); s2 += __shfl_xor(s2, off); }
    __shared__ float rs[4], rs2[4];
    if ((t & 63) == 0) { rs[t >> 6] = s; rs2[t >> 6] = s2; }
    __syncthreads();
    s  = rs[0] + rs[1] + rs[2] + rs[3];
    s2 = rs2[0] + rs2[1] + rs2[2] + rs2[3];
    const float mu  = s * (1.0f / 2048.0f);
    const float var = s2 * (1.0f / 2048.0f) - mu * mu;
    const float rstd = rsqrtf(var + 1e-5f);
    #pragma unroll
    for (int k = 0; k < 8; ++k) {
        const int idx = t + k * 256;
        out[b * HH + idx] = (x[k] - mu) * rstd * gamma[idx] + beta[idx];
    }
}

extern "C" void kernel_launch(void* const* d_in, const int* in_sizes, int n_in,
                              void* d_out, int out_size, void* d_ws, size_t ws_size,
                              hipStream_t stream)
{
    const float* views = (const float*)d_in[0];
    const float* Wq   = (const float*)d_in[1];  const float* bq   = (const float*)d_in[2];
    const float* Wk   = (const float*)d_in[3];  const float* bk   = (const float*)d_in[4];
    const float* Wv   = (const float*)d_in[5];  const float* bv   = (const float*)d_in[6];
    const float* Wiq  = (const float*)d_in[7];  const float* biq  = (const float*)d_in[8];
    const float* Wik  = (const float*)d_in[9];  const float* bik  = (const float*)d_in[10];
    const float* Wiv  = (const float*)d_in[11]; const float* biv  = (const float*)d_in[12];
    const float* Wo   = (const float*)d_in[13]; const float* bo   = (const float*)d_in[14];
    const float* Wout = (const float*)d_in[15]; const float* bout = (const float*)d_in[16];
    const float* gamma= (const float*)d_in[17]; const float* beta = (const float*)d_in[18];

    static bool attr_set = false;
    if (!attr_set) {
        hipFuncSetAttribute((const void*)gemm256<false,false>,
                            hipFuncAttributeMaxDynamicSharedMemorySize, LDS_TOTAL);
        hipFuncSetAttribute((const void*)gemm256<true,true>,
                            hipFuncAttributeMaxDynamicSharedMemorySize, LDS_TOTAL);
        hipFuncSetAttribute((const void*)gemm_fold,
                            hipFuncAttributeMaxDynamicSharedMemorySize, LDS_TOTAL);
        attr_set = true;
    }

    // ---- workspace: persistent folded weights + overlaid {fold-scratch | activations} ----
    char* ws = (char*)d_ws;
    bf16_t* WQ2  = (bf16_t*)ws;                  // 3u folded q
    bf16_t* WK2  = WQ2 + 3*WUNIT;                // 6u folded k (per pair)
    bf16_t* WV2  = WK2 + 6*WUNIT;                // 6u folded v
    bf16_t* WFIN = WV2 + 6*WUNIT;                // 3u folded final, [2048][6144]
    float*  BQ2  = (float*)(WFIN + 3*WUNIT);
    float*  BK2  = BQ2 + 3*HH;
    float*  BV2  = BK2 + 6*HH;
    float*  BFIN = BV2 + 6*HH;
    const long FIXED = 18L*WUNIT*2 + 16L*HH*4;   // 151,126,016 B

    char* R = ws + FIXED;
    // fold-phase transient (dead before activations are written):
    bf16_t* WIQ   = (bf16_t*)R;
    bf16_t* WIK   = WIQ  + 3*WUNIT;
    bf16_t* WIV   = WIK  + 3*WUNIT;
    bf16_t* WOUTB = WIV  + 3*WUNIT;
    bf16_t* WQT   = WOUTB+ 3*WUNIT;
    bf16_t* WKT   = WQT  + 3*WUNIT;
    bf16_t* WVT   = WKT  + 3*WUNIT;
    bf16_t* WOT   = WVT  + 3*WUNIT;              // scratch total 24u = 201.3 MB

    // ---- adaptive batch chunking ----
    const long scratch = 24L*WUNIT*2;
    long Bc = 8192;
    while (Bc > 256) {
        long need = Bc * 73728L; if (need < scratch) need = scratch;
        if (FIXED + need <= (long)ws_size) break;
        Bc >>= 1;
    }
    const int mshift = __builtin_ctzl((unsigned long)Bc) - 8;  // log2(Bc/256)
    const int bshift = __builtin_ctzl((unsigned long)Bc);      // log2(Bc)
    const long S1 = Bc * HH;

    bf16_t* VBF = (bf16_t*)R;            // views bf16 -> later ctx (3 slabs)
    bf16_t* Q2B = VBF + 3*S1;            // q2 (3)
    bf16_t* K2  = Q2B + 3*S1;            // k2 (6)
    bf16_t* V2  = K2  + 6*S1;            // v2 (6)
    float*  PROJ= (float*)K2;            // aliases K2 (dead after attn)

    const SlabMap mp3  = {{0,1,2,0,0,0},{0,1,2,0,0,0}};
    const SlabMap mp6k = {{1,2,0,2,0,1},{0,1,2,3,4,5}};  // a = oth[v][j], w = pair idx
    const SlabMap mp1  = {{0,0,0,0,0,0},{0,0,0,0,0,0}};
    const int oth[3][2] = {{1,2},{0,2},{0,1}};

    // ---- one-time: weight conversions (2 batched dispatches) ----
    {
        Ptrs4 c1 = {{Wiq, Wik, Wiv, Wout}, {WIQ, WIK, WIV, WOUTB}};
        f2b4_kernel<<<8192, 256, 0, stream>>>(c1);
        Ptrs4 c2 = {{Wq, Wk, Wv, Wo}, {WQT, WKT, WVT, WOT}};
        f2bT4_kernel<<<12288, 256, 0, stream>>>(c2);
    }
    // ---- one-time: all 18 weight-fold GEMMs in ONE dispatch ----
    {
        GJobs js;
        for (int v = 0; v < 3; ++v)
            js.j[v] = { WIQ + (long)v*WUNIT, WQT + (long)v*WUNIT, WQ2 + (long)v*WUNIT, 2048, 2048 };
        for (int v = 0; v < 3; ++v)
            for (int j = 0; j < 2; ++j) {
                const int p = v*2 + j, o = oth[v][j];
                js.j[3 + p] = { WIK + (long)v*WUNIT, WKT + (long)o*WUNIT, WK2 + (long)p*WUNIT, 2048, 2048 };
                js.j[9 + p] = { WIV + (long)v*WUNIT, WVT + (long)o*WUNIT, WV2 + (long)p*WUNIT, 2048, 2048 };
            }
        for (int v = 0; v < 3; ++v)
            js.j[15 + v] = { WOUTB + (long)v*2048, WOT + (long)v*WUNIT, WFIN + (long)v*2048, 6144, 6144 };
        gemm_fold<<<1152, 512, LDS_TOTAL, stream>>>(js);
    }
    // ---- one-time: all 16 exact bias folds in one dispatch ----
    {
        FoldPack fp;
        for (int v = 0; v < 3; ++v)
            fp.j[v] = { Wiq + (long)v*WUNIT, bq + v*HH, biq + v*HH, BQ2 + v*HH, 2048 };
        for (int v = 0; v < 3; ++v)
            for (int j = 0; j < 2; ++j) {
                const int p = v*2 + j, o = oth[v][j];
                fp.j[3 + p] = { Wik + (long)v*WUNIT, bk + o*HH, bik + v*HH, BK2 + p*HH, 2048 };
                fp.j[9 + p] = { Wiv + (long)v*WUNIT, bv + o*HH, biv + v*HH, BV2 + p*HH, 2048 };
            }
        fp.j[15] = { Wout, bo, bout, BFIN, 6144 };
        biasfold_all<<<32768, 256, 0, stream>>>(fp);
    }

    const int nwg3 = 8 * 3 * (int)(Bc >> 8);
    const int nwg6 = 8 * 6 * (int)(Bc >> 8);
    const int nwg1 = 8 * 1 * (int)(Bc >> 8);
    const int vgrid = (int)((S1 / 1024 > 8192) ? 8192 : S1 / 1024);

    for (long b0 = 0; b0 < BB; b0 += Bc) {
        if (Bc == 8192) {
            f2b_kernel<<<8192, 256, 0, stream>>>(views, VBF, 3*BH);
        } else {
            for (int v = 0; v < 3; ++v)
                f2b_kernel<<<vgrid, 256, 0, stream>>>(views + v*BH + b0*HH, VBF + v*S1, S1);
        }
        // q2 / k2 / v2 directly from views via folded weights
        gemm256<false,false><<<nwg3, 512, LDS_TOTAL, stream>>>(VBF, 2048, S1, mp3,  mshift, WQ2, 2048, BQ2, (void*)Q2B, 2048, S1, 2048);
        gemm256<false,false><<<nwg6, 512, LDS_TOTAL, stream>>>(VBF, 2048, S1, mp6k, mshift, WK2, 2048, BK2, (void*)K2,  2048, S1, 2048);
        gemm256<false,false><<<nwg6, 512, LDS_TOTAL, stream>>>(VBF, 2048, S1, mp6k, mshift, WV2, 2048, BV2, (void*)V2,  2048, S1, 2048);
        // attention: ctx -> VBF (views_bf dead)
        attn_kernel<<<(int)(12*Bc), 256, 0, stream>>>(Q2B, K2, V2, VBF, bshift);
        // fused projection: proj = sum_v ctx[v] @ WFIN_v^T + BFIN (K=6144 over ctx slabs)
        gemm256<true,true><<<nwg1, 512, LDS_TOTAL, stream>>>(VBF, 2048, S1, mp1, mshift, WFIN, 6144, BFIN, (void*)PROJ, 2048, 0, 6144);
        // residual + LayerNorm
        ln_kernel<<<(int)Bc, 256, 0, stream>>>(PROJ, views + b0*HH, gamma, beta, ((float*)d_out) + b0*HH);
    }
}